// Round 1
// 686.558 us; speedup vs baseline: 1.5829x; 1.5829x over previous
//
#include <hip/hip_runtime.h>
#include <cstdint>
#include <cstddef>

// ---------------- problem constants ----------------
#define NBATCH 8
#define MID 256
#define HIMG 64
#define WIMG 64
#define NA 9
#define NPRE 6000
#define NPOST 300
#define NANCH (HIMG*WIMG*NA)   // 36864
#define NWORDS 94              // ceil(6000/64)
#define GCOLS 6016             // 94*64 padded columns

// output float offsets
#define OUT_LOC   0
#define OUT_SCORE 1179648
#define OUT_ROIS  1769472
#define OUT_RIDX  1779072
#define OUT_ANCH  1781472

// workspace byte offsets
#define H_OFF    0ul
#define H_BYTES  (8ul*256*64*64*4)         // 33554432
#define WT_OFF   (H_OFF + H_BYTES)
#define WT_BYTES (2304ul*256*4)            // 2359296 = exactly w2h+w2l (half)
#define BOX_OFF  (WT_OFF + WT_BYTES)
#define BOX_BYTES (8ul*36864*4*4)          // 4718592
#define U_OFF    (BOX_OFF + BOX_BYTES)
#define U_BYTES  (8ul*36864*4)
#define CK_OFF   (U_OFF + U_BYTES)
#define CK_BYTES (8ul*8192*8)
#define CC_OFF   (CK_OFF + CK_BYTES)
#define CC_BYTES 64ul
#define BK_OFF   (CC_OFF + CC_BYTES)
#define BK_BYTES (8ul*6000*16)
#define M_OFF    (BK_OFF + BK_BYTES + 64)
#define M_BYTES  (8ul*NWORDS*GCOLS*8)      // 36.2 MB, column-major mask

typedef _Float16 f16x8 __attribute__((ext_vector_type(8)));
typedef float f32x16 __attribute__((ext_vector_type(16)));

#define GLD_LDS16(gptr, lptr) __builtin_amdgcn_global_load_lds( \
    (const __attribute__((address_space(1))) void*)(gptr),      \
    (__attribute__((address_space(3))) void*)(lptr), 16, 0, 0)

// ---------------- weight prep: conv1_w[oc][ic][ky][kx] -> w2{h,l}[s][oc][ic] fp16 hi/lo ----------------
// lo part is scaled by 2^11 so it stays in the fp16 normal range (denormal-flush-proof).
__global__ __launch_bounds__(256) void k_prep_w(const float* __restrict__ w,
                                                _Float16* __restrict__ w2h,
                                                _Float16* __restrict__ w2l) {
    int idx = blockIdx.x * 256 + threadIdx.x;   // s*65536 + oc*256 + ic, total 589824
    if (idx >= 589824) return;
    int s = idx >> 16;
    int rem = idx & 65535;
    int oc = rem >> 8, ic = rem & 255;
    float v = w[(oc * 256 + ic) * 9 + s];
    _Float16 vh = (_Float16)v;
    float r = v - (float)vh;                    // exact in fp32
    w2h[idx] = vh;
    w2l[idx] = (_Float16)(r * 2048.0f);
}

// ---------------- anchors output (exact double->f32 like numpy) + zero counters ----------------
__global__ void k_anchors(float* __restrict__ out, unsigned int* __restrict__ cc) {
    int idx = blockIdx.x * 256 + threadIdx.x;
    if (blockIdx.x == 0 && threadIdx.x < 16) cc[threadIdx.x] = 0u;
    if (idx >= NANCH) return;
    int p = idx / 9, a = idx - p * 9;
    int y = p >> 6, xg = p & 63;
    double rr = (a < 3) ? 0.5 : ((a < 6) ? 1.0 : 2.0);
    int sj = a % 3;
    double ssc = (sj == 0) ? 8.0 : ((sj == 1) ? 16.0 : 32.0);
    double hh = 7.0 * ssc * sqrt(rr);
    double ww = 7.0 * ssc * sqrt(1.0 / rr);
    float a0 = (float)(3.5 - 0.5 * hh), a2 = (float)(3.5 + 0.5 * hh);
    float b0 = (float)(3.5 - 0.5 * ww), b2 = (float)(3.5 + 0.5 * ww);
    float* dst = out + OUT_ANCH + (size_t)idx * 4;
    dst[0] = y * 16.0f + a0;
    dst[1] = xg * 16.0f + b0;
    dst[2] = y * 16.0f + a2;
    dst[3] = xg * 16.0f + b2;
}

// ---------------- conv1 3x3 + bias + relu via fp16 hi/lo split MFMA (3-term emulation) ----------------
// C[oc,p] = sum_s sum_ic W_s[oc,ic] * X[ic, p+delta_s]  (9 shifted GEMMs, K=2304 total)
// acc1 += Ah*Bh ; acc2 += Ah*Bl' + Al'*Bh ; result = acc1 + acc2 * 2^-11
// Block: 256 oc x 128 px (2 image rows). 8 waves = 4 (oc) x 2 (row). mfma_f32_32x32x16_f16.
__global__ __launch_bounds__(512) void k_conv1m(const float* __restrict__ x,
                                                const _Float16* __restrict__ w2h,
                                                const _Float16* __restrict__ w2l,
                                                const float* __restrict__ bias,
                                                float* __restrict__ h) {
    __shared__ __align__(16) _Float16 at[2][2][4096];   // [buf][hi/lo][oc*16 + icg*8 + e]  32 KB
    __shared__ __align__(16) _Float16 bt[2][6144];      // [hi/lo][(r*64+col)*24 + ii]      24 KB
    __shared__ float bsh[256];

    const int tid = threadIdx.x;
    const int lane = tid & 63;
    const int wv = tid >> 6;        // 0..7
    const int wm = wv >> 1;         // 0..3 : oc block 64*wm
    const int wn = wv & 1;          // 0..1 : image row y0+wn
    const int y0 = blockIdx.x * 2;
    const int n  = blockIdx.y;

    if (tid < 256) bsh[tid] = bias[tid];

    const float* xn = x + (size_t)n * 1048576;

    f32x16 acc1[2][2], acc2[2][2];
#pragma unroll
    for (int i = 0; i < 2; ++i)
#pragma unroll
        for (int j = 0; j < 2; ++j)
#pragma unroll
            for (int e = 0; e < 16; ++e) { acc1[i][j][e] = 0.0f; acc2[i][j][e] = 0.0f; }

    // --- staging geometry (wave-uniform halo-row / ic-group) ---
    const int scol = lane;          // 0..63
    const int sr   = wv & 3;        // halo row 0..3 -> gy = y0-1+sr
    const int siig = wv >> 2;       // ic-subgroup 0..1 (8 ic each)
    const int sgy  = y0 - 1 + sr;
    const bool gyok = (sgy >= 0) && (sgy < 64);
    const float* xrow = xn + sgy * 64 + scol;

    // per-lane part of w2 source offset: oc = 32*wv + (lane>>1), icg = lane&1
    const int at_src_lane = ((32 * wv + (lane >> 1)) << 8) + ((lane & 1) << 3);

    // A-fragment LDS half-offsets: lane reads at[oc][ (lane>>5)*8 .. +8 ]
    const int aoff0 = ((wm * 64 + (lane & 31)) << 4) + ((lane >> 5) << 3);
    const int aoff1 = aoff0 + 512;  // +32 oc
    const int bl31 = lane & 31;
    const int bg = (lane >> 5) << 3;

    auto stage_at = [&](int buf, int kb2, int s2) {
        const _Float16* ph = w2h + (s2 << 16) + (kb2 << 4) + at_src_lane;
        const _Float16* pl = w2l + (s2 << 16) + (kb2 << 4) + at_src_lane;
        GLD_LDS16(ph, &at[buf][0][wv << 9]);
        GLD_LDS16(pl, &at[buf][1][wv << 9]);
    };

    stage_at(0, 0, 0);   // prologue prefetch (kb=0, s=0)

    for (int kb = 0; kb < 16; ++kb) {
        __syncthreads();   // previous bt fully consumed
        // ---- stage B halo tile for this ic-block: fp32 -> hi/lo fp16, rows y0-1..y0+2 ----
        {
            f16x8 hh, hl;
            const float* px = xrow + (size_t)(kb * 16 + siig * 8) * 4096;
#pragma unroll
            for (int q = 0; q < 8; ++q) {
                float v = gyok ? px[(size_t)q * 4096] : 0.0f;
                _Float16 vh = (_Float16)v;
                float rr = v - (float)vh;
                hh[q] = vh;
                hl[q] = (_Float16)(rr * 2048.0f);
            }
            const int bto = (sr * 64 + scol) * 24 + siig * 8;
            *(f16x8*)&bt[0][bto] = hh;
            *(f16x8*)&bt[1][bto] = hl;
        }
        __syncthreads();   // bt ready; at[buf] for (kb,0) landed (barrier drains vmcnt)

#pragma unroll
        for (int s = 0; s < 9; ++s) {
            const int step = kb * 9 + s;
            const int buf = step & 1;
            if (step + 1 < 144)
                stage_at(buf ^ 1, (s == 8) ? (kb + 1) : kb, (s == 8) ? 0 : (s + 1));

            const _Float16* ath = &at[buf][0][0];
            const _Float16* atl = &at[buf][1][0];
            f16x8 Ah0 = *(const f16x8*)(ath + aoff0);
            f16x8 Ah1 = *(const f16x8*)(ath + aoff1);
            f16x8 Al0 = *(const f16x8*)(atl + aoff0);
            f16x8 Al1 = *(const f16x8*)(atl + aoff1);

            const int dy = s / 3 - 1, dx = s % 3 - 1;
            const int rb = (wn + dy + 1) * 64;
            const f16x8 ZF = {};
            f16x8 Bh0, Bl0, Bh1, Bl1;
            {
                const int c0 = bl31 + dx;                  // -1..32
                const int cc0 = (c0 < 0) ? 0 : c0;
                const int bo0 = (rb + cc0) * 24 + bg;
                Bh0 = *(const f16x8*)&bt[0][bo0];
                Bl0 = *(const f16x8*)&bt[1][bo0];
                if ((unsigned)c0 >= 64u) { Bh0 = ZF; Bl0 = ZF; }
                const int c1 = bl31 + 32 + dx;             // 31..64
                const int cc1 = (c1 > 63) ? 63 : c1;
                const int bo1 = (rb + cc1) * 24 + bg;
                Bh1 = *(const f16x8*)&bt[0][bo1];
                Bl1 = *(const f16x8*)&bt[1][bo1];
                if ((unsigned)c1 >= 64u) { Bh1 = ZF; Bl1 = ZF; }
            }

            acc1[0][0] = __builtin_amdgcn_mfma_f32_32x32x16_f16(Ah0, Bh0, acc1[0][0], 0, 0, 0);
            acc1[0][1] = __builtin_amdgcn_mfma_f32_32x32x16_f16(Ah0, Bh1, acc1[0][1], 0, 0, 0);
            acc1[1][0] = __builtin_amdgcn_mfma_f32_32x32x16_f16(Ah1, Bh0, acc1[1][0], 0, 0, 0);
            acc1[1][1] = __builtin_amdgcn_mfma_f32_32x32x16_f16(Ah1, Bh1, acc1[1][1], 0, 0, 0);
            acc2[0][0] = __builtin_amdgcn_mfma_f32_32x32x16_f16(Ah0, Bl0, acc2[0][0], 0, 0, 0);
            acc2[0][1] = __builtin_amdgcn_mfma_f32_32x32x16_f16(Ah0, Bl1, acc2[0][1], 0, 0, 0);
            acc2[1][0] = __builtin_amdgcn_mfma_f32_32x32x16_f16(Ah1, Bl0, acc2[1][0], 0, 0, 0);
            acc2[1][1] = __builtin_amdgcn_mfma_f32_32x32x16_f16(Ah1, Bl1, acc2[1][1], 0, 0, 0);
            acc2[0][0] = __builtin_amdgcn_mfma_f32_32x32x16_f16(Al0, Bh0, acc2[0][0], 0, 0, 0);
            acc2[0][1] = __builtin_amdgcn_mfma_f32_32x32x16_f16(Al0, Bh1, acc2[0][1], 0, 0, 0);
            acc2[1][0] = __builtin_amdgcn_mfma_f32_32x32x16_f16(Al1, Bh0, acc2[1][0], 0, 0, 0);
            acc2[1][1] = __builtin_amdgcn_mfma_f32_32x32x16_f16(Al1, Bh1, acc2[1][1], 0, 0, 0);
            __syncthreads();   // protects at double-buffer + drains next-step DMA
        }
    }

    // ---- epilogue: combine hi/lo accs, bias, relu, store ----
    // C/D 32x32 layout: col = lane&31, row = (reg&3) + 8*(reg>>2) + 4*(lane>>5)
    const int colw = lane & 31;
    const int rgh = (lane >> 5) * 4;
    float* hn = h + (size_t)n * 1048576 + (size_t)(y0 + wn) * 64;
#pragma unroll
    for (int ocb = 0; ocb < 2; ++ocb)
#pragma unroll
        for (int pcb = 0; pcb < 2; ++pcb)
#pragma unroll
            for (int reg = 0; reg < 16; ++reg) {
                const int row = (reg & 3) + 8 * (reg >> 2) + rgh;
                const int oc = wm * 64 + ocb * 32 + row;
                float v = acc1[ocb][pcb][reg] + acc2[ocb][pcb][reg] * 4.8828125e-4f + bsh[oc];
                hn[(size_t)oc * 4096 + pcb * 32 + colw] = fmaxf(v, 0.0f);
            }
}

// ---------------- 1x1 heads — unchanged (verified) ----------------
__global__ __launch_bounds__(256) void k_heads(const float* __restrict__ h,
                                               const float* __restrict__ loc_w,
                                               const float* __restrict__ score_w,
                                               const float* __restrict__ loc_b,
                                               const float* __restrict__ score_b,
                                               const int* __restrict__ ihp,
                                               const int* __restrict__ iwp,
                                               float* __restrict__ out,
                                               float* __restrict__ boxes,
                                               unsigned int* __restrict__ ubuf) {
    __shared__ float Wl[54 * 64];     // [c][kk]
    __shared__ float outb[128 * 57];  // [p][c] pitch 57
    const int tid = threadIdx.x;
    const int pl = tid & 127, chalf = tid >> 7;
    const int c0 = chalf * 27;
    const int ptile = blockIdx.x;
    const int n = blockIdx.y;
    const int pg = ptile * 128 + pl;

    float acc[27];
#pragma unroll
    for (int i = 0; i < 27; ++i) acc[i] = 0.f;

    for (int kc = 0; kc < 4; ++kc) {
        __syncthreads();
        for (int idx = tid; idx < 54 * 64; idx += 256) {
            int c = idx >> 6, kk = idx & 63;
            int gk = kc * 64 + kk;
            Wl[idx] = (c < 36) ? loc_w[c * 256 + gk] : score_w[(c - 36) * 256 + gk];
        }
        __syncthreads();
        for (int k4 = 0; k4 < 64; k4 += 4) {
            int gk = kc * 64 + k4;
            float hv0 = h[(n * 256 + gk + 0) * 4096 + pg];
            float hv1 = h[(n * 256 + gk + 1) * 4096 + pg];
            float hv2 = h[(n * 256 + gk + 2) * 4096 + pg];
            float hv3 = h[(n * 256 + gk + 3) * 4096 + pg];
#pragma unroll
            for (int ci = 0; ci < 27; ++ci) {
                float4 w4 = *(const float4*)&Wl[(c0 + ci) * 64 + k4];
                acc[ci] += hv0 * w4.x + hv1 * w4.y + hv2 * w4.z + hv3 * w4.w;
            }
        }
    }
#pragma unroll
    for (int ci = 0; ci < 27; ++ci) {
        int c = c0 + ci;
        float bv = (c < 36) ? loc_b[c] : score_b[c - 36];
        outb[pl * 57 + c] = acc[ci] + bv;
    }
    __syncthreads();

    const float fh = (float)(*ihp), fwid = (float)(*iwp);
    for (int slot = tid; slot < 128 * 9; slot += 256) {
        int pli = slot / 9, a = slot - pli * 9;
        int p = ptile * 128 + pli;
        int y = p >> 6, xg = p & 63;
        float l0 = outb[pli * 57 + a * 4 + 0];
        float l1 = outb[pli * 57 + a * 4 + 1];
        float l2 = outb[pli * 57 + a * 4 + 2];
        float l3 = outb[pli * 57 + a * 4 + 3];
        float s0 = outb[pli * 57 + 36 + a * 2 + 0];
        float s1 = outb[pli * 57 + 36 + a * 2 + 1];
        size_t base = (size_t)n * NANCH + (size_t)p * 9 + a;
        ((float4*)(out + OUT_LOC))[base] = make_float4(l0, l1, l2, l3);
        ((float2*)(out + OUT_SCORE))[base] = make_float2(s0, s1);
        float mx = fmaxf(s0, s1);
        float e0 = expf(s0 - mx), e1 = expf(s1 - mx);
        float fg = e1 / (e0 + e1);
        double rr = (a < 3) ? 0.5 : ((a < 6) ? 1.0 : 2.0);
        int sj = a % 3;
        double ssc = (sj == 0) ? 8.0 : ((sj == 1) ? 16.0 : 32.0);
        double hhd = 7.0 * ssc * sqrt(rr);
        double wwd = 7.0 * ssc * sqrt(1.0 / rr);
        float a0 = (float)(3.5 - 0.5 * hhd), a2 = (float)(3.5 + 0.5 * hhd);
        float b0 = (float)(3.5 - 0.5 * wwd), b2 = (float)(3.5 + 0.5 * wwd);
        float ay1 = y * 16.0f + a0, ay2 = y * 16.0f + a2;
        float ax1 = xg * 16.0f + b0, ax2 = xg * 16.0f + b2;
        float ah = ay2 - ay1, aw = ax2 - ax1;
        float acy = ay1 + 0.5f * ah, acx = ax1 + 0.5f * aw;
        float cy = l0 * ah + acy, cx = l1 * aw + acx;
        float bh = expf(l2) * ah, bw = expf(l3) * aw;
        float y1 = fminf(fmaxf(cy - 0.5f * bh, 0.f), fh);
        float x1 = fminf(fmaxf(cx - 0.5f * bw, 0.f), fwid);
        float y2 = fminf(fmaxf(cy + 0.5f * bh, 0.f), fh);
        float x2 = fminf(fmaxf(cx + 0.5f * bw, 0.f), fwid);
        ((float4*)boxes)[base] = make_float4(y1, x1, y2, x2);
        bool valid = ((y2 - y1) >= 16.0f) && ((x2 - x1) >= 16.0f);
        float sc = valid ? fg : -__builtin_inff();
        unsigned int ub = __float_as_uint(sc);
        ub = (ub & 0x80000000u) ? ~ub : (ub | 0x80000000u);
        ubuf[base] = ub;
    }
}

// ---------------- exact top-6000 per batch: byte-radix select + compact (unchanged) ----------------
__global__ __launch_bounds__(1024) void k_select(const unsigned int* __restrict__ ubuf,
                                                 unsigned long long* __restrict__ ckeys,
                                                 unsigned int* __restrict__ cc) {
    __shared__ unsigned int hist[256];
    __shared__ unsigned int selb;
    __shared__ int rank_s;
    __shared__ unsigned int lcnt;
    const int tid = threadIdx.x;
    const int b = blockIdx.x;
    const unsigned int* ub = ubuf + (size_t)b * NANCH;
    if (tid == 0) { rank_s = NPRE - 1; lcnt = 0; }
    unsigned int prefix = 0;
    for (int pass = 0; pass < 4; ++pass) {
        int shift = 24 - 8 * pass;
        if (tid < 256) hist[tid] = 0;
        __syncthreads();
        for (int i = tid; i < NANCH; i += 1024) {
            unsigned int u = ub[i];
            bool ok = (pass == 0) || ((u >> (shift + 8)) == (prefix >> (shift + 8)));
            if (ok) atomicAdd(&hist[(u >> shift) & 255], 1u);
        }
        __syncthreads();
        if (tid == 0) {
            int racc = 0; unsigned int bs = 0; int r = rank_s;
            for (int bb = 255; bb >= 0; --bb) {
                int c = (int)hist[bb];
                if (racc + c > r) { bs = (unsigned int)bb; rank_s = r - racc; break; }
                racc += c;
            }
            selb = bs;
        }
        __syncthreads();
        prefix |= (selb << shift);
        __syncthreads();
    }
    const unsigned int ustar = prefix;
    for (int i = tid; i < NANCH; i += 1024) {
        unsigned int u = ub[i];
        if (u >= ustar) {
            unsigned int pos = atomicAdd(&lcnt, 1u);
            if (pos < 8192)
                ckeys[(size_t)b * 8192 + pos] =
                    ((unsigned long long)u << 32) | (unsigned int)(0xFFFFFFFFu - (unsigned int)i);
        }
    }
    __syncthreads();
    if (tid == 0) cc[b] = (lcnt > 8192u) ? 8192u : lcnt;
}

// ---------------- bitonic sort 8192 composite keys + gather boxes (unchanged) ----------------
__global__ __launch_bounds__(1024) void k_sort(const unsigned long long* __restrict__ ckeys,
                                               const unsigned int* __restrict__ cc,
                                               const float* __restrict__ boxes,
                                               float* __restrict__ bk) {
    __shared__ unsigned long long S[8192];
    const int tid = threadIdx.x;
    const int b = blockIdx.x;
    const int cnt = (int)cc[b];
    for (int i = tid; i < 8192; i += 1024)
        S[i] = (i < cnt) ? ckeys[(size_t)b * 8192 + i] : 0ull;
    __syncthreads();
    for (int k = 2; k <= 8192; k <<= 1) {
        for (int j = k >> 1; j > 0; j >>= 1) {
            for (int i = tid; i < 8192; i += 1024) {
                int l = i ^ j;
                if (l > i) {
                    unsigned long long av = S[i], cv = S[l];
                    bool desc = ((i & k) == 0);
                    bool sw = desc ? (av < cv) : (av > cv);
                    if (sw) { S[i] = cv; S[l] = av; }
                }
            }
            __syncthreads();
        }
    }
    for (int i = tid; i < NPRE; i += 1024) {
        unsigned long long key = S[i];
        unsigned int idx = 0xFFFFFFFFu - (unsigned int)(key & 0xFFFFFFFFull);
        if (idx >= NANCH) idx = NANCH - 1;   // safety
        float4 bx = ((const float4*)boxes)[(size_t)b * NANCH + idx];
        ((float4*)bk)[(size_t)b * NPRE + i] = bx;
    }
}

// ---------------- IoU bitmask, COLUMN-major (unchanged) ----------------
__global__ __launch_bounds__(256) void k_mask(const float* __restrict__ bk,
                                              unsigned long long* __restrict__ MT) {
    const int iw = blockIdx.x;
    const int gb = blockIdx.y;
    const int b = blockIdx.z;
    if (iw > 4 * gb + 3) return;
    const int tid = threadIdx.x;
    __shared__ float4 jb[64];
    if (tid < 64) {
        int j = iw * 64 + tid;
        jb[tid] = (j < NPRE) ? ((const float4*)bk)[(size_t)b * NPRE + j]
                             : make_float4(0.f, 0.f, 0.f, 0.f);
    }
    __syncthreads();
    const int g = gb * 256 + tid;
    float4 bi = (g < NPRE) ? ((const float4*)bk)[(size_t)b * NPRE + g]
                           : make_float4(0.f, 0.f, 0.f, 0.f);
    float ai = (bi.z - bi.x) * (bi.w - bi.y);
    unsigned long long word = 0ull;
#pragma unroll 4
    for (int jj = 0; jj < 64; ++jj) {
        float4 bj = jb[jj];
        float ty = fmaxf(bi.x, bj.x), tx = fmaxf(bi.y, bj.y);
        float by = fminf(bi.z, bj.z), bx = fminf(bi.w, bj.w);
        float ihh = fmaxf(by - ty, 0.f), iww = fmaxf(bx - tx, 0.f);
        float inter = ihh * iww;
        float aj = (bj.z - bj.x) * (bj.w - bj.y);
        float iou = inter / (ai + aj - inter + 1e-9f);
        if (iou > 0.7f) word |= (1ull << jj);
    }
    if (g < GCOLS)
        MT[((size_t)b * NWORDS + iw) * GCOLS + g] = word;
}

// ---------------- greedy NMS with early break (unchanged) ----------------
__global__ __launch_bounds__(1024) void k_nms(const unsigned long long* __restrict__ MT,
                                              const float* __restrict__ bk,
                                              float* __restrict__ out) {
    const int b = blockIdx.x;
    const int tid = threadIdx.x;
    const int lane = tid & 63;
    __shared__ unsigned long long keptw[NWORDS];
    __shared__ unsigned long long dead[NWORDS];
    __shared__ int sel[NPOST];
    __shared__ int totkept;
    const unsigned long long* mtb = MT + (size_t)b * NWORDS * GCOLS;

    for (int i = tid; i < NWORDS; i += 1024) { dead[i] = 0ull; keptw[i] = 0ull; }
    if (tid == 0) totkept = 0;
    __syncthreads();

    for (int c = 0; c < NWORDS; ++c) {
        if (tid < 64) {   // wave 0: in-chunk greedy closure
            const int g = c * 64 + lane;
            unsigned long long diag = mtb[(size_t)c * GCOLS + g];
            bool deadl = (((dead[c] >> lane) & 1ull) != 0ull) || (g >= NPRE);
            unsigned long long undec = ~__ballot(deadl);
            unsigned long long kc = 0ull;
            while (undec) {
                int i = __builtin_ctzll(undec);
                kc |= (1ull << i);
                unsigned long long supm = __ballot((diag >> i) & 1ull);
                undec &= ~(supm | (1ull << i));
            }
            if (lane == 0) { keptw[c] = kc; totkept += __popcll(kc); }
        }
        __syncthreads();
        if (totkept >= NPOST) break;          // later chunks can't affect the output
        const unsigned long long kc = keptw[c];
        if (kc) {
            for (int g2 = (c + 1) * 64 + tid; g2 < GCOLS; g2 += 1024) {
                unsigned long long w = mtb[(size_t)c * GCOLS + g2] & kc;
                unsigned long long m = __ballot(w != 0ull);
                if (lane == 0 && m) atomicOr(&dead[g2 >> 6], m);
            }
        }
        __syncthreads();
    }

    if (tid == 0) {
        int pos = 0;
        for (int w = 0; w < NWORDS && pos < NPOST; ++w) {
            unsigned long long kw = keptw[w];
            while (kw && pos < NPOST) {
                int i2 = __builtin_ctzll(kw);
                sel[pos++] = w * 64 + i2;
                kw &= kw - 1;
            }
        }
        for (int w = 0; w < NWORDS && pos < NPOST; ++w) {
            int nvalid = NPRE - w * 64; if (nvalid > 64) nvalid = 64;
            unsigned long long vm = (nvalid >= 64) ? ~0ull : ((1ull << nvalid) - 1ull);
            unsigned long long sw = (~keptw[w]) & vm;
            while (sw && pos < NPOST) {
                int i2 = __builtin_ctzll(sw);
                sel[pos++] = w * 64 + i2;
                sw &= sw - 1;
            }
        }
    }
    __syncthreads();
    for (int s2 = tid; s2 < NPOST; s2 += 1024) {
        int i = sel[s2];
        float4 bx = ((const float4*)bk)[(size_t)b * NPRE + i];
        ((float4*)(out + OUT_ROIS))[b * NPOST + s2] = bx;
        out[OUT_RIDX + b * NPOST + s2] = (float)b;
    }
}

// ---------------- launch ----------------
extern "C" void kernel_launch(void* const* d_in, const int* in_sizes, int n_in,
                              void* d_out, int out_size, void* d_ws, size_t ws_size,
                              hipStream_t stream) {
    const float* x = (const float*)d_in[0];
    const float* conv1_w = (const float*)d_in[1];
    const float* conv1_b = (const float*)d_in[2];
    const float* score_w = (const float*)d_in[3];
    const float* score_b = (const float*)d_in[4];
    const float* loc_w = (const float*)d_in[5];
    const float* loc_b = (const float*)d_in[6];
    const int* ihp = (const int*)d_in[7];
    const int* iwp = (const int*)d_in[8];
    float* out = (float*)d_out;
    char* ws = (char*)d_ws;
    float* h = (float*)(ws + H_OFF);
    _Float16* w2h = (_Float16*)(ws + WT_OFF);
    _Float16* w2l = (_Float16*)(ws + WT_OFF + 1179648ul);
    float* boxes = (float*)(ws + BOX_OFF);
    unsigned int* ubuf = (unsigned int*)(ws + U_OFF);
    unsigned long long* ckeys = (unsigned long long*)(ws + CK_OFF);
    unsigned int* cc = (unsigned int*)(ws + CC_OFF);
    float* bk = (float*)(ws + BK_OFF);
    unsigned long long* MT = (unsigned long long*)(ws + M_OFF);

    hipLaunchKernelGGL(k_prep_w, dim3(2304), dim3(256), 0, stream, conv1_w, w2h, w2l);
    hipLaunchKernelGGL(k_anchors, dim3(144), dim3(256), 0, stream, out, cc);
    hipLaunchKernelGGL(k_conv1m, dim3(32, 8), dim3(512), 0, stream, x, w2h, w2l, conv1_b, h);
    hipLaunchKernelGGL(k_heads, dim3(32, 8), dim3(256), 0, stream,
                       h, loc_w, score_w, loc_b, score_b, ihp, iwp, out, boxes, ubuf);
    hipLaunchKernelGGL(k_select, dim3(8), dim3(1024), 0, stream, ubuf, ckeys, cc);
    hipLaunchKernelGGL(k_sort, dim3(8), dim3(1024), 0, stream, ckeys, cc, boxes, bk);
    hipLaunchKernelGGL(k_mask, dim3(94, 24, 8), dim3(256), 0, stream, bk, MT);
    hipLaunchKernelGGL(k_nms, dim3(8), dim3(1024), 0, stream, MT, bk, out);
}

// Round 2
// 670.365 us; speedup vs baseline: 1.6212x; 1.0242x over previous
//
#include <hip/hip_runtime.h>
#include <cstdint>
#include <cstddef>

// ---------------- problem constants ----------------
#define NBATCH 8
#define MID 256
#define HIMG 64
#define WIMG 64
#define NA 9
#define NPRE 6000
#define NPOST 300
#define NANCH (HIMG*WIMG*NA)   // 36864
#define NWORDS 94              // ceil(6000/64)
#define GCOLS 6016             // 94*64 padded columns

// output float offsets
#define OUT_LOC   0
#define OUT_SCORE 1179648
#define OUT_ROIS  1769472
#define OUT_RIDX  1779072
#define OUT_ANCH  1781472

// workspace byte offsets
#define H_OFF    0ul
#define H_BYTES  (8ul*256*64*64*4)         // 33554432
#define WT_OFF   (H_OFF + H_BYTES)
#define WT_BYTES (2304ul*256*4)            // 2359296 = exactly w3h+w3l (half)
#define BOX_OFF  (WT_OFF + WT_BYTES)
#define BOX_BYTES (8ul*36864*4*4)          // 4718592
#define U_OFF    (BOX_OFF + BOX_BYTES)
#define U_BYTES  (8ul*36864*4)
#define CK_OFF   (U_OFF + U_BYTES)
#define CK_BYTES (8ul*8192*8)
#define CC_OFF   (CK_OFF + CK_BYTES)
#define CC_BYTES 64ul
#define BK_OFF   (CC_OFF + CC_BYTES)
#define BK_BYTES (8ul*6000*16)
#define M_OFF    (BK_OFF + BK_BYTES + 64)
#define M_BYTES  (8ul*NWORDS*GCOLS*8)      // 36.2 MB, column-major mask

typedef _Float16 f16x8 __attribute__((ext_vector_type(8)));
typedef float f32x16 __attribute__((ext_vector_type(16)));

// ---------------- weight prep: conv1_w[oc][ic][ky][kx] -> w3{h,l}[s][kb][g][oc][8] fp16 hi/lo ----------
// Fragment-major layout: each lane's 8-ic A-fragment is 16 contiguous bytes; 32 consecutive oc
// fragments are a contiguous 512B segment -> coalesced global_load_dwordx4 straight to registers.
// lo part scaled by 2^11 to stay in fp16 normal range.
__global__ __launch_bounds__(256) void k_prep_w(const float* __restrict__ w,
                                                _Float16* __restrict__ w3h,
                                                _Float16* __restrict__ w3l) {
    int idx = blockIdx.x * 256 + threadIdx.x;   // 589824 = 9*16*2*256*8
    if (idx >= 589824) return;
    int e  = idx & 7;
    int t  = idx >> 3;
    int oc = t & 255; t >>= 8;
    int g  = t & 1;   t >>= 1;
    int kb = t & 15;  t >>= 4;
    int s  = t;                               // 0..8
    int ic = kb * 16 + g * 8 + e;
    float v = w[(oc * 256 + ic) * 9 + s];
    _Float16 vh = (_Float16)v;
    float r = v - (float)vh;                  // exact in fp32
    w3h[idx] = vh;
    w3l[idx] = (_Float16)(r * 2048.0f);
}

// ---------------- anchors output (exact double->f32 like numpy) + zero counters ----------------
__global__ void k_anchors(float* __restrict__ out, unsigned int* __restrict__ cc) {
    int idx = blockIdx.x * 256 + threadIdx.x;
    if (blockIdx.x == 0 && threadIdx.x < 16) cc[threadIdx.x] = 0u;
    if (idx >= NANCH) return;
    int p = idx / 9, a = idx - p * 9;
    int y = p >> 6, xg = p & 63;
    double rr = (a < 3) ? 0.5 : ((a < 6) ? 1.0 : 2.0);
    int sj = a % 3;
    double ssc = (sj == 0) ? 8.0 : ((sj == 1) ? 16.0 : 32.0);
    double hh = 7.0 * ssc * sqrt(rr);
    double ww = 7.0 * ssc * sqrt(1.0 / rr);
    float a0 = (float)(3.5 - 0.5 * hh), a2 = (float)(3.5 + 0.5 * hh);
    float b0 = (float)(3.5 - 0.5 * ww), b2 = (float)(3.5 + 0.5 * ww);
    float* dst = out + OUT_ANCH + (size_t)idx * 4;
    dst[0] = y * 16.0f + a0;
    dst[1] = xg * 16.0f + b0;
    dst[2] = y * 16.0f + a2;
    dst[3] = xg * 16.0f + b2;
}

// ---------------- conv1 3x3 + bias + relu via fp16 hi/lo split MFMA (3-term emulation) ----------------
// A operands: direct global->register (L1/L2-resident weights, coalesced 16B/lane).
// B tile: single LDS buffer per kb, pitch 26 halves (odd dword stride -> bank-conflict-free),
// zero-padded halo cols -1/64 (no per-step clamps). NO barriers inside the 9-tap loop.
__global__ __launch_bounds__(512, 2) void k_conv1m(const float* __restrict__ x,
                                                   const _Float16* __restrict__ w3h,
                                                   const _Float16* __restrict__ w3l,
                                                   const float* __restrict__ bias,
                                                   float* __restrict__ h) {
    // bt entry = (row 0..3)*66 + colp 0..65 ; entry stride 26 halves (16 used: g*8+e)
    __shared__ __align__(16) _Float16 bt0[4 * 66 * 26];   // hi: 13728 B
    __shared__ __align__(16) _Float16 bt1[4 * 66 * 26];   // lo
    __shared__ float bsh[256];

    const int tid = threadIdx.x;
    const int lane = tid & 63;
    const int wv = tid >> 6;        // 0..7
    const int wm = wv >> 1;         // 0..3 : oc block 64*wm
    const int wn = wv & 1;          // 0..1 : image row y0+wn
    const int y0 = blockIdx.x * 2;
    const int n  = blockIdx.y;
    const int bl31 = lane & 31;
    const int g = lane >> 5;        // ic-subgroup for fragments

    // zero entire bt once (covers pad cols -1/64; interior rewritten every kb)
    for (int i = tid; i < 858; i += 512) {          // 858*8 = 6864 halves
        ((f16x8*)bt0)[i] = (f16x8){};
        ((f16x8*)bt1)[i] = (f16x8){};
    }
    if (tid < 256) bsh[tid] = bias[tid];

    f32x16 acc1[2][2], acc2[2][2];
#pragma unroll
    for (int i = 0; i < 2; ++i)
#pragma unroll
        for (int j = 0; j < 2; ++j)
#pragma unroll
            for (int e = 0; e < 16; ++e) { acc1[i][j][e] = 0.0f; acc2[i][j][e] = 0.0f; }

    // --- staging geometry (wave-uniform halo-row / ic-group) ---
    const int scol = lane;          // 0..63
    const int sr   = wv & 3;        // halo row 0..3 -> gy = y0-1+sr
    const int siig = wv >> 2;       // ic-subgroup 0..1 (8 ic each)
    const int sgy  = y0 - 1 + sr;
    const bool gyok = (sgy >= 0) && (sgy < 64);
    const float* xrow = x + (size_t)n * 1048576 + sgy * 64 + scol;
    const int bto = (sr * 66 + scol + 1) * 26 + siig * 8;

    // A fragment offset (halves) within one (s,kb) slab: (g*256 + oc)*8, oc = wm*64 + ocb*32 + bl31
    const int aoffl = (g * 256 + wm * 64 + bl31) * 8;

    float xr[8];
#pragma unroll
    for (int q = 0; q < 8; ++q)
        xr[q] = gyok ? xrow[(size_t)(siig * 8 + q) * 4096] : 0.0f;

    for (int kb = 0; kb < 16; ++kb) {
        __syncthreads();            // previous bt fully consumed (kb=0: after zero-init)
        {
            f16x8 hh, hl;
#pragma unroll
            for (int q = 0; q < 8; ++q) {
                float v = xr[q];
                _Float16 vh = (_Float16)v;
                hh[q] = vh;
                hl[q] = (_Float16)((v - (float)vh) * 2048.0f);
            }
            *(f16x8*)&bt0[bto] = hh;
            *(f16x8*)&bt1[bto] = hl;
        }
        __syncthreads();            // bt ready
        if (kb < 15) {              // prefetch next kb's x rows; consumed after next barrier
#pragma unroll
            for (int q = 0; q < 8; ++q)
                xr[q] = gyok ? xrow[(size_t)((kb + 1) * 16 + siig * 8 + q) * 4096] : 0.0f;
        }
        const _Float16* wkh = w3h + (size_t)kb * 4096;
        const _Float16* wkl = w3l + (size_t)kb * 4096;
#pragma unroll
        for (int s = 0; s < 9; ++s) {
            const _Float16* ph = wkh + (size_t)s * 65536;
            const _Float16* pl = wkl + (size_t)s * 65536;
            f16x8 Ah0 = *(const f16x8*)(ph + aoffl);
            f16x8 Ah1 = *(const f16x8*)(ph + aoffl + 256);
            f16x8 Al0 = *(const f16x8*)(pl + aoffl);
            f16x8 Al1 = *(const f16x8*)(pl + aoffl + 256);

            const int dy = s / 3 - 1, dx = s % 3 - 1;
            const int entry0 = (wn + dy + 1) * 66 + dx + 1 + bl31;   // pcb=0
            const int e0 = entry0 * 26 + g * 8;
            const int e1 = (entry0 + 32) * 26 + g * 8;               // pcb=1
            f16x8 Bh0 = *(const f16x8*)&bt0[e0];
            f16x8 Bl0 = *(const f16x8*)&bt1[e0];
            f16x8 Bh1 = *(const f16x8*)&bt0[e1];
            f16x8 Bl1 = *(const f16x8*)&bt1[e1];

            acc1[0][0] = __builtin_amdgcn_mfma_f32_32x32x16_f16(Ah0, Bh0, acc1[0][0], 0, 0, 0);
            acc1[0][1] = __builtin_amdgcn_mfma_f32_32x32x16_f16(Ah0, Bh1, acc1[0][1], 0, 0, 0);
            acc1[1][0] = __builtin_amdgcn_mfma_f32_32x32x16_f16(Ah1, Bh0, acc1[1][0], 0, 0, 0);
            acc1[1][1] = __builtin_amdgcn_mfma_f32_32x32x16_f16(Ah1, Bh1, acc1[1][1], 0, 0, 0);
            acc2[0][0] = __builtin_amdgcn_mfma_f32_32x32x16_f16(Ah0, Bl0, acc2[0][0], 0, 0, 0);
            acc2[0][1] = __builtin_amdgcn_mfma_f32_32x32x16_f16(Ah0, Bl1, acc2[0][1], 0, 0, 0);
            acc2[1][0] = __builtin_amdgcn_mfma_f32_32x32x16_f16(Ah1, Bl0, acc2[1][0], 0, 0, 0);
            acc2[1][1] = __builtin_amdgcn_mfma_f32_32x32x16_f16(Ah1, Bl1, acc2[1][1], 0, 0, 0);
            acc2[0][0] = __builtin_amdgcn_mfma_f32_32x32x16_f16(Al0, Bh0, acc2[0][0], 0, 0, 0);
            acc2[0][1] = __builtin_amdgcn_mfma_f32_32x32x16_f16(Al0, Bh1, acc2[0][1], 0, 0, 0);
            acc2[1][0] = __builtin_amdgcn_mfma_f32_32x32x16_f16(Al1, Bh0, acc2[1][0], 0, 0, 0);
            acc2[1][1] = __builtin_amdgcn_mfma_f32_32x32x16_f16(Al1, Bh1, acc2[1][1], 0, 0, 0);
        }
    }

    // ---- epilogue: combine hi/lo accs, bias, relu, store ----
    // C/D 32x32 layout: col = lane&31, row = (reg&3) + 8*(reg>>2) + 4*(lane>>5)
    const int colw = lane & 31;
    const int rgh = (lane >> 5) * 4;
    float* hn = h + (size_t)n * 1048576 + (size_t)(y0 + wn) * 64;
#pragma unroll
    for (int ocb = 0; ocb < 2; ++ocb)
#pragma unroll
        for (int pcb = 0; pcb < 2; ++pcb)
#pragma unroll
            for (int reg = 0; reg < 16; ++reg) {
                const int row = (reg & 3) + 8 * (reg >> 2) + rgh;
                const int oc = wm * 64 + ocb * 32 + row;
                float v = acc1[ocb][pcb][reg] + acc2[ocb][pcb][reg] * 4.8828125e-4f + bsh[oc];
                hn[(size_t)oc * 4096 + pcb * 32 + colw] = fmaxf(v, 0.0f);
            }
}

// ---------------- 1x1 heads — unchanged (verified) ----------------
__global__ __launch_bounds__(256) void k_heads(const float* __restrict__ h,
                                               const float* __restrict__ loc_w,
                                               const float* __restrict__ score_w,
                                               const float* __restrict__ loc_b,
                                               const float* __restrict__ score_b,
                                               const int* __restrict__ ihp,
                                               const int* __restrict__ iwp,
                                               float* __restrict__ out,
                                               float* __restrict__ boxes,
                                               unsigned int* __restrict__ ubuf) {
    __shared__ float Wl[54 * 64];     // [c][kk]
    __shared__ float outb[128 * 57];  // [p][c] pitch 57
    const int tid = threadIdx.x;
    const int pl = tid & 127, chalf = tid >> 7;
    const int c0 = chalf * 27;
    const int ptile = blockIdx.x;
    const int n = blockIdx.y;
    const int pg = ptile * 128 + pl;

    float acc[27];
#pragma unroll
    for (int i = 0; i < 27; ++i) acc[i] = 0.f;

    for (int kc = 0; kc < 4; ++kc) {
        __syncthreads();
        for (int idx = tid; idx < 54 * 64; idx += 256) {
            int c = idx >> 6, kk = idx & 63;
            int gk = kc * 64 + kk;
            Wl[idx] = (c < 36) ? loc_w[c * 256 + gk] : score_w[(c - 36) * 256 + gk];
        }
        __syncthreads();
        for (int k4 = 0; k4 < 64; k4 += 4) {
            int gk = kc * 64 + k4;
            float hv0 = h[(n * 256 + gk + 0) * 4096 + pg];
            float hv1 = h[(n * 256 + gk + 1) * 4096 + pg];
            float hv2 = h[(n * 256 + gk + 2) * 4096 + pg];
            float hv3 = h[(n * 256 + gk + 3) * 4096 + pg];
#pragma unroll
            for (int ci = 0; ci < 27; ++ci) {
                float4 w4 = *(const float4*)&Wl[(c0 + ci) * 64 + k4];
                acc[ci] += hv0 * w4.x + hv1 * w4.y + hv2 * w4.z + hv3 * w4.w;
            }
        }
    }
#pragma unroll
    for (int ci = 0; ci < 27; ++ci) {
        int c = c0 + ci;
        float bv = (c < 36) ? loc_b[c] : score_b[c - 36];
        outb[pl * 57 + c] = acc[ci] + bv;
    }
    __syncthreads();

    const float fh = (float)(*ihp), fwid = (float)(*iwp);
    for (int slot = tid; slot < 128 * 9; slot += 256) {
        int pli = slot / 9, a = slot - pli * 9;
        int p = ptile * 128 + pli;
        int y = p >> 6, xg = p & 63;
        float l0 = outb[pli * 57 + a * 4 + 0];
        float l1 = outb[pli * 57 + a * 4 + 1];
        float l2 = outb[pli * 57 + a * 4 + 2];
        float l3 = outb[pli * 57 + a * 4 + 3];
        float s0 = outb[pli * 57 + 36 + a * 2 + 0];
        float s1 = outb[pli * 57 + 36 + a * 2 + 1];
        size_t base = (size_t)n * NANCH + (size_t)p * 9 + a;
        ((float4*)(out + OUT_LOC))[base] = make_float4(l0, l1, l2, l3);
        ((float2*)(out + OUT_SCORE))[base] = make_float2(s0, s1);
        float mx = fmaxf(s0, s1);
        float e0 = expf(s0 - mx), e1 = expf(s1 - mx);
        float fg = e1 / (e0 + e1);
        double rr = (a < 3) ? 0.5 : ((a < 6) ? 1.0 : 2.0);
        int sj = a % 3;
        double ssc = (sj == 0) ? 8.0 : ((sj == 1) ? 16.0 : 32.0);
        double hhd = 7.0 * ssc * sqrt(rr);
        double wwd = 7.0 * ssc * sqrt(1.0 / rr);
        float a0 = (float)(3.5 - 0.5 * hhd), a2 = (float)(3.5 + 0.5 * hhd);
        float b0 = (float)(3.5 - 0.5 * wwd), b2 = (float)(3.5 + 0.5 * wwd);
        float ay1 = y * 16.0f + a0, ay2 = y * 16.0f + a2;
        float ax1 = xg * 16.0f + b0, ax2 = xg * 16.0f + b2;
        float ah = ay2 - ay1, aw = ax2 - ax1;
        float acy = ay1 + 0.5f * ah, acx = ax1 + 0.5f * aw;
        float cy = l0 * ah + acy, cx = l1 * aw + acx;
        float bh = expf(l2) * ah, bw = expf(l3) * aw;
        float y1 = fminf(fmaxf(cy - 0.5f * bh, 0.f), fh);
        float x1 = fminf(fmaxf(cx - 0.5f * bw, 0.f), fwid);
        float y2 = fminf(fmaxf(cy + 0.5f * bh, 0.f), fh);
        float x2 = fminf(fmaxf(cx + 0.5f * bw, 0.f), fwid);
        ((float4*)boxes)[base] = make_float4(y1, x1, y2, x2);
        bool valid = ((y2 - y1) >= 16.0f) && ((x2 - x1) >= 16.0f);
        float sc = valid ? fg : -__builtin_inff();
        unsigned int ub = __float_as_uint(sc);
        ub = (ub & 0x80000000u) ? ~ub : (ub | 0x80000000u);
        ubuf[base] = ub;
    }
}

// ---------------- exact top-6000 per batch: byte-radix select + compact (unchanged) ----------------
__global__ __launch_bounds__(1024) void k_select(const unsigned int* __restrict__ ubuf,
                                                 unsigned long long* __restrict__ ckeys,
                                                 unsigned int* __restrict__ cc) {
    __shared__ unsigned int hist[256];
    __shared__ unsigned int selb;
    __shared__ int rank_s;
    __shared__ unsigned int lcnt;
    const int tid = threadIdx.x;
    const int b = blockIdx.x;
    const unsigned int* ub = ubuf + (size_t)b * NANCH;
    if (tid == 0) { rank_s = NPRE - 1; lcnt = 0; }
    unsigned int prefix = 0;
    for (int pass = 0; pass < 4; ++pass) {
        int shift = 24 - 8 * pass;
        if (tid < 256) hist[tid] = 0;
        __syncthreads();
        for (int i = tid; i < NANCH; i += 1024) {
            unsigned int u = ub[i];
            bool ok = (pass == 0) || ((u >> (shift + 8)) == (prefix >> (shift + 8)));
            if (ok) atomicAdd(&hist[(u >> shift) & 255], 1u);
        }
        __syncthreads();
        if (tid == 0) {
            int racc = 0; unsigned int bs = 0; int r = rank_s;
            for (int bb = 255; bb >= 0; --bb) {
                int c = (int)hist[bb];
                if (racc + c > r) { bs = (unsigned int)bb; rank_s = r - racc; break; }
                racc += c;
            }
            selb = bs;
        }
        __syncthreads();
        prefix |= (selb << shift);
        __syncthreads();
    }
    const unsigned int ustar = prefix;
    for (int i = tid; i < NANCH; i += 1024) {
        unsigned int u = ub[i];
        if (u >= ustar) {
            unsigned int pos = atomicAdd(&lcnt, 1u);
            if (pos < 8192)
                ckeys[(size_t)b * 8192 + pos] =
                    ((unsigned long long)u << 32) | (unsigned int)(0xFFFFFFFFu - (unsigned int)i);
        }
    }
    __syncthreads();
    if (tid == 0) cc[b] = (lcnt > 8192u) ? 8192u : lcnt;
}

// ---------------- bitonic sort 8192 composite keys + gather boxes (unchanged) ----------------
__global__ __launch_bounds__(1024) void k_sort(const unsigned long long* __restrict__ ckeys,
                                               const unsigned int* __restrict__ cc,
                                               const float* __restrict__ boxes,
                                               float* __restrict__ bk) {
    __shared__ unsigned long long S[8192];
    const int tid = threadIdx.x;
    const int b = blockIdx.x;
    const int cnt = (int)cc[b];
    for (int i = tid; i < 8192; i += 1024)
        S[i] = (i < cnt) ? ckeys[(size_t)b * 8192 + i] : 0ull;
    __syncthreads();
    for (int k = 2; k <= 8192; k <<= 1) {
        for (int j = k >> 1; j > 0; j >>= 1) {
            for (int i = tid; i < 8192; i += 1024) {
                int l = i ^ j;
                if (l > i) {
                    unsigned long long av = S[i], cv = S[l];
                    bool desc = ((i & k) == 0);
                    bool sw = desc ? (av < cv) : (av > cv);
                    if (sw) { S[i] = cv; S[l] = av; }
                }
            }
            __syncthreads();
        }
    }
    for (int i = tid; i < NPRE; i += 1024) {
        unsigned long long key = S[i];
        unsigned int idx = 0xFFFFFFFFu - (unsigned int)(key & 0xFFFFFFFFull);
        if (idx >= NANCH) idx = NANCH - 1;   // safety
        float4 bx = ((const float4*)boxes)[(size_t)b * NANCH + idx];
        ((float4*)bk)[(size_t)b * NPRE + i] = bx;
    }
}

// ---------------- IoU bitmask, COLUMN-major (unchanged) ----------------
__global__ __launch_bounds__(256) void k_mask(const float* __restrict__ bk,
                                              unsigned long long* __restrict__ MT) {
    const int iw = blockIdx.x;
    const int gb = blockIdx.y;
    const int b = blockIdx.z;
    if (iw > 4 * gb + 3) return;
    const int tid = threadIdx.x;
    __shared__ float4 jb[64];
    if (tid < 64) {
        int j = iw * 64 + tid;
        jb[tid] = (j < NPRE) ? ((const float4*)bk)[(size_t)b * NPRE + j]
                             : make_float4(0.f, 0.f, 0.f, 0.f);
    }
    __syncthreads();
    const int g = gb * 256 + tid;
    float4 bi = (g < NPRE) ? ((const float4*)bk)[(size_t)b * NPRE + g]
                           : make_float4(0.f, 0.f, 0.f, 0.f);
    float ai = (bi.z - bi.x) * (bi.w - bi.y);
    unsigned long long word = 0ull;
#pragma unroll 4
    for (int jj = 0; jj < 64; ++jj) {
        float4 bj = jb[jj];
        float ty = fmaxf(bi.x, bj.x), tx = fmaxf(bi.y, bj.y);
        float by = fminf(bi.z, bj.z), bx = fminf(bi.w, bj.w);
        float ihh = fmaxf(by - ty, 0.f), iww = fmaxf(bx - tx, 0.f);
        float inter = ihh * iww;
        float aj = (bj.z - bj.x) * (bj.w - bj.y);
        float iou = inter / (ai + aj - inter + 1e-9f);
        if (iou > 0.7f) word |= (1ull << jj);
    }
    if (g < GCOLS)
        MT[((size_t)b * NWORDS + iw) * GCOLS + g] = word;
}

// ---------------- greedy NMS with early break (unchanged) ----------------
__global__ __launch_bounds__(1024) void k_nms(const unsigned long long* __restrict__ MT,
                                              const float* __restrict__ bk,
                                              float* __restrict__ out) {
    const int b = blockIdx.x;
    const int tid = threadIdx.x;
    const int lane = tid & 63;
    __shared__ unsigned long long keptw[NWORDS];
    __shared__ unsigned long long dead[NWORDS];
    __shared__ int sel[NPOST];
    __shared__ int totkept;
    const unsigned long long* mtb = MT + (size_t)b * NWORDS * GCOLS;

    for (int i = tid; i < NWORDS; i += 1024) { dead[i] = 0ull; keptw[i] = 0ull; }
    if (tid == 0) totkept = 0;
    __syncthreads();

    for (int c = 0; c < NWORDS; ++c) {
        if (tid < 64) {   // wave 0: in-chunk greedy closure
            const int g = c * 64 + lane;
            unsigned long long diag = mtb[(size_t)c * GCOLS + g];
            bool deadl = (((dead[c] >> lane) & 1ull) != 0ull) || (g >= NPRE);
            unsigned long long undec = ~__ballot(deadl);
            unsigned long long kc = 0ull;
            while (undec) {
                int i = __builtin_ctzll(undec);
                kc |= (1ull << i);
                unsigned long long supm = __ballot((diag >> i) & 1ull);
                undec &= ~(supm | (1ull << i));
            }
            if (lane == 0) { keptw[c] = kc; totkept += __popcll(kc); }
        }
        __syncthreads();
        if (totkept >= NPOST) break;          // later chunks can't affect the output
        const unsigned long long kc = keptw[c];
        if (kc) {
            for (int g2 = (c + 1) * 64 + tid; g2 < GCOLS; g2 += 1024) {
                unsigned long long w = mtb[(size_t)c * GCOLS + g2] & kc;
                unsigned long long m = __ballot(w != 0ull);
                if (lane == 0 && m) atomicOr(&dead[g2 >> 6], m);
            }
        }
        __syncthreads();
    }

    if (tid == 0) {
        int pos = 0;
        for (int w = 0; w < NWORDS && pos < NPOST; ++w) {
            unsigned long long kw = keptw[w];
            while (kw && pos < NPOST) {
                int i2 = __builtin_ctzll(kw);
                sel[pos++] = w * 64 + i2;
                kw &= kw - 1;
            }
        }
        for (int w = 0; w < NWORDS && pos < NPOST; ++w) {
            int nvalid = NPRE - w * 64; if (nvalid > 64) nvalid = 64;
            unsigned long long vm = (nvalid >= 64) ? ~0ull : ((1ull << nvalid) - 1ull);
            unsigned long long sw = (~keptw[w]) & vm;
            while (sw && pos < NPOST) {
                int i2 = __builtin_ctzll(sw);
                sel[pos++] = w * 64 + i2;
                sw &= sw - 1;
            }
        }
    }
    __syncthreads();
    for (int s2 = tid; s2 < NPOST; s2 += 1024) {
        int i = sel[s2];
        float4 bx = ((const float4*)bk)[(size_t)b * NPRE + i];
        ((float4*)(out + OUT_ROIS))[b * NPOST + s2] = bx;
        out[OUT_RIDX + b * NPOST + s2] = (float)b;
    }
}

// ---------------- launch ----------------
extern "C" void kernel_launch(void* const* d_in, const int* in_sizes, int n_in,
                              void* d_out, int out_size, void* d_ws, size_t ws_size,
                              hipStream_t stream) {
    const float* x = (const float*)d_in[0];
    const float* conv1_w = (const float*)d_in[1];
    const float* conv1_b = (const float*)d_in[2];
    const float* score_w = (const float*)d_in[3];
    const float* score_b = (const float*)d_in[4];
    const float* loc_w = (const float*)d_in[5];
    const float* loc_b = (const float*)d_in[6];
    const int* ihp = (const int*)d_in[7];
    const int* iwp = (const int*)d_in[8];
    float* out = (float*)d_out;
    char* ws = (char*)d_ws;
    float* h = (float*)(ws + H_OFF);
    _Float16* w3h = (_Float16*)(ws + WT_OFF);
    _Float16* w3l = (_Float16*)(ws + WT_OFF + 1179648ul);
    float* boxes = (float*)(ws + BOX_OFF);
    unsigned int* ubuf = (unsigned int*)(ws + U_OFF);
    unsigned long long* ckeys = (unsigned long long*)(ws + CK_OFF);
    unsigned int* cc = (unsigned int*)(ws + CC_OFF);
    float* bk = (float*)(ws + BK_OFF);
    unsigned long long* MT = (unsigned long long*)(ws + M_OFF);

    hipLaunchKernelGGL(k_prep_w, dim3(2304), dim3(256), 0, stream, conv1_w, w3h, w3l);
    hipLaunchKernelGGL(k_anchors, dim3(144), dim3(256), 0, stream, out, cc);
    hipLaunchKernelGGL(k_conv1m, dim3(32, 8), dim3(512), 0, stream, x, w3h, w3l, conv1_b, h);
    hipLaunchKernelGGL(k_heads, dim3(32, 8), dim3(256), 0, stream,
                       h, loc_w, score_w, loc_b, score_b, ihp, iwp, out, boxes, ubuf);
    hipLaunchKernelGGL(k_select, dim3(8), dim3(1024), 0, stream, ubuf, ckeys, cc);
    hipLaunchKernelGGL(k_sort, dim3(8), dim3(1024), 0, stream, ckeys, cc, boxes, bk);
    hipLaunchKernelGGL(k_mask, dim3(94, 24, 8), dim3(256), 0, stream, bk, MT);
    hipLaunchKernelGGL(k_nms, dim3(8), dim3(1024), 0, stream, MT, bk, out);
}

// Round 3
// 623.554 us; speedup vs baseline: 1.7429x; 1.0751x over previous
//
#include <hip/hip_runtime.h>
#include <cstdint>
#include <cstddef>

// ---------------- problem constants ----------------
#define NBATCH 8
#define MID 256
#define HIMG 64
#define WIMG 64
#define NA 9
#define NPRE 6000
#define NPOST 300
#define NANCH (HIMG*WIMG*NA)   // 36864
#define NWORDS 94              // ceil(6000/64)
#define GCOLS 6016             // 94*64 padded columns

// output float offsets
#define OUT_LOC   0
#define OUT_SCORE 1179648
#define OUT_ROIS  1769472
#define OUT_RIDX  1779072
#define OUT_ANCH  1781472

// workspace byte offsets
#define H_OFF    0ul
#define H_BYTES  (8ul*256*64*64*4)         // 33554432
#define WT_OFF   (H_OFF + H_BYTES)
#define WT_BYTES (2304ul*256*4)            // 2359296 = exactly w3h+w3l (half)
#define BOX_OFF  (WT_OFF + WT_BYTES)
#define BOX_BYTES (8ul*36864*4*4)          // 4718592
#define U_OFF    (BOX_OFF + BOX_BYTES)
#define U_BYTES  (8ul*36864*4)
#define CK_OFF   (U_OFF + U_BYTES)
#define CK_BYTES (8ul*8192*8)
#define CC_OFF   (CK_OFF + CK_BYTES)
#define CC_BYTES 64ul
#define BK_OFF   (CC_OFF + CC_BYTES)
#define BK_BYTES (8ul*6000*16)
#define M_OFF    (BK_OFF + BK_BYTES + 64)
#define M_BYTES  (8ul*NWORDS*GCOLS*8)      // 36.2 MB, column-major mask

typedef _Float16 f16x8 __attribute__((ext_vector_type(8)));
typedef float f32x16 __attribute__((ext_vector_type(16)));

// ---------------- weight prep: conv1_w[oc][ic][ky][kx] -> w3{h,l}[s][kb][g][oc][8] fp16 hi/lo ----------
__global__ __launch_bounds__(256) void k_prep_w(const float* __restrict__ w,
                                                _Float16* __restrict__ w3h,
                                                _Float16* __restrict__ w3l) {
    int idx = blockIdx.x * 256 + threadIdx.x;   // 589824 = 9*16*2*256*8
    if (idx >= 589824) return;
    int e  = idx & 7;
    int t  = idx >> 3;
    int oc = t & 255; t >>= 8;
    int g  = t & 1;   t >>= 1;
    int kb = t & 15;  t >>= 4;
    int s  = t;                               // 0..8
    int ic = kb * 16 + g * 8 + e;
    float v = w[(oc * 256 + ic) * 9 + s];
    _Float16 vh = (_Float16)v;
    float r = v - (float)vh;                  // exact in fp32
    w3h[idx] = vh;
    w3l[idx] = (_Float16)(r * 2048.0f);
}

// ---------------- anchors output (exact double->f32 like numpy) + zero counters ----------------
__global__ void k_anchors(float* __restrict__ out, unsigned int* __restrict__ cc) {
    int idx = blockIdx.x * 256 + threadIdx.x;
    if (blockIdx.x == 0 && threadIdx.x < 16) cc[threadIdx.x] = 0u;
    if (idx >= NANCH) return;
    int p = idx / 9, a = idx - p * 9;
    int y = p >> 6, xg = p & 63;
    double rr = (a < 3) ? 0.5 : ((a < 6) ? 1.0 : 2.0);
    int sj = a % 3;
    double ssc = (sj == 0) ? 8.0 : ((sj == 1) ? 16.0 : 32.0);
    double hh = 7.0 * ssc * sqrt(rr);
    double ww = 7.0 * ssc * sqrt(1.0 / rr);
    float a0 = (float)(3.5 - 0.5 * hh), a2 = (float)(3.5 + 0.5 * hh);
    float b0 = (float)(3.5 - 0.5 * ww), b2 = (float)(3.5 + 0.5 * ww);
    float* dst = out + OUT_ANCH + (size_t)idx * 4;
    dst[0] = y * 16.0f + a0;
    dst[1] = xg * 16.0f + b0;
    dst[2] = y * 16.0f + a2;
    dst[3] = xg * 16.0f + b2;
}

// ---------------- conv1 3x3 + bias + relu via fp16 hi/lo split MFMA (unchanged from R2) ----------------
__global__ __launch_bounds__(512, 2) void k_conv1m(const float* __restrict__ x,
                                                   const _Float16* __restrict__ w3h,
                                                   const _Float16* __restrict__ w3l,
                                                   const float* __restrict__ bias,
                                                   float* __restrict__ h) {
    __shared__ __align__(16) _Float16 bt0[4 * 66 * 26];   // hi
    __shared__ __align__(16) _Float16 bt1[4 * 66 * 26];   // lo
    __shared__ float bsh[256];

    const int tid = threadIdx.x;
    const int lane = tid & 63;
    const int wv = tid >> 6;        // 0..7
    const int wm = wv >> 1;         // 0..3 : oc block 64*wm
    const int wn = wv & 1;          // 0..1 : image row y0+wn
    const int y0 = blockIdx.x * 2;
    const int n  = blockIdx.y;
    const int bl31 = lane & 31;
    const int g = lane >> 5;        // ic-subgroup for fragments

    for (int i = tid; i < 858; i += 512) {
        ((f16x8*)bt0)[i] = (f16x8){};
        ((f16x8*)bt1)[i] = (f16x8){};
    }
    if (tid < 256) bsh[tid] = bias[tid];

    f32x16 acc1[2][2], acc2[2][2];
#pragma unroll
    for (int i = 0; i < 2; ++i)
#pragma unroll
        for (int j = 0; j < 2; ++j)
#pragma unroll
            for (int e = 0; e < 16; ++e) { acc1[i][j][e] = 0.0f; acc2[i][j][e] = 0.0f; }

    const int scol = lane;
    const int sr   = wv & 3;
    const int siig = wv >> 2;
    const int sgy  = y0 - 1 + sr;
    const bool gyok = (sgy >= 0) && (sgy < 64);
    const float* xrow = x + (size_t)n * 1048576 + sgy * 64 + scol;
    const int bto = (sr * 66 + scol + 1) * 26 + siig * 8;

    const int aoffl = (g * 256 + wm * 64 + bl31) * 8;

    float xr[8];
#pragma unroll
    for (int q = 0; q < 8; ++q)
        xr[q] = gyok ? xrow[(size_t)(siig * 8 + q) * 4096] : 0.0f;

    for (int kb = 0; kb < 16; ++kb) {
        __syncthreads();
        {
            f16x8 hh, hl;
#pragma unroll
            for (int q = 0; q < 8; ++q) {
                float v = xr[q];
                _Float16 vh = (_Float16)v;
                hh[q] = vh;
                hl[q] = (_Float16)((v - (float)vh) * 2048.0f);
            }
            *(f16x8*)&bt0[bto] = hh;
            *(f16x8*)&bt1[bto] = hl;
        }
        __syncthreads();
        if (kb < 15) {
#pragma unroll
            for (int q = 0; q < 8; ++q)
                xr[q] = gyok ? xrow[(size_t)((kb + 1) * 16 + siig * 8 + q) * 4096] : 0.0f;
        }
        const _Float16* wkh = w3h + (size_t)kb * 4096;
        const _Float16* wkl = w3l + (size_t)kb * 4096;
#pragma unroll
        for (int s = 0; s < 9; ++s) {
            const _Float16* ph = wkh + (size_t)s * 65536;
            const _Float16* pl = wkl + (size_t)s * 65536;
            f16x8 Ah0 = *(const f16x8*)(ph + aoffl);
            f16x8 Ah1 = *(const f16x8*)(ph + aoffl + 256);
            f16x8 Al0 = *(const f16x8*)(pl + aoffl);
            f16x8 Al1 = *(const f16x8*)(pl + aoffl + 256);

            const int dy = s / 3 - 1, dx = s % 3 - 1;
            const int entry0 = (wn + dy + 1) * 66 + dx + 1 + bl31;
            const int e0 = entry0 * 26 + g * 8;
            const int e1 = (entry0 + 32) * 26 + g * 8;
            f16x8 Bh0 = *(const f16x8*)&bt0[e0];
            f16x8 Bl0 = *(const f16x8*)&bt1[e0];
            f16x8 Bh1 = *(const f16x8*)&bt0[e1];
            f16x8 Bl1 = *(const f16x8*)&bt1[e1];

            acc1[0][0] = __builtin_amdgcn_mfma_f32_32x32x16_f16(Ah0, Bh0, acc1[0][0], 0, 0, 0);
            acc1[0][1] = __builtin_amdgcn_mfma_f32_32x32x16_f16(Ah0, Bh1, acc1[0][1], 0, 0, 0);
            acc1[1][0] = __builtin_amdgcn_mfma_f32_32x32x16_f16(Ah1, Bh0, acc1[1][0], 0, 0, 0);
            acc1[1][1] = __builtin_amdgcn_mfma_f32_32x32x16_f16(Ah1, Bh1, acc1[1][1], 0, 0, 0);
            acc2[0][0] = __builtin_amdgcn_mfma_f32_32x32x16_f16(Ah0, Bl0, acc2[0][0], 0, 0, 0);
            acc2[0][1] = __builtin_amdgcn_mfma_f32_32x32x16_f16(Ah0, Bl1, acc2[0][1], 0, 0, 0);
            acc2[1][0] = __builtin_amdgcn_mfma_f32_32x32x16_f16(Ah1, Bl0, acc2[1][0], 0, 0, 0);
            acc2[1][1] = __builtin_amdgcn_mfma_f32_32x32x16_f16(Ah1, Bl1, acc2[1][1], 0, 0, 0);
            acc2[0][0] = __builtin_amdgcn_mfma_f32_32x32x16_f16(Al0, Bh0, acc2[0][0], 0, 0, 0);
            acc2[0][1] = __builtin_amdgcn_mfma_f32_32x32x16_f16(Al0, Bh1, acc2[0][1], 0, 0, 0);
            acc2[1][0] = __builtin_amdgcn_mfma_f32_32x32x16_f16(Al1, Bh0, acc2[1][0], 0, 0, 0);
            acc2[1][1] = __builtin_amdgcn_mfma_f32_32x32x16_f16(Al1, Bh1, acc2[1][1], 0, 0, 0);
        }
    }

    const int colw = lane & 31;
    const int rgh = (lane >> 5) * 4;
    float* hn = h + (size_t)n * 1048576 + (size_t)(y0 + wn) * 64;
#pragma unroll
    for (int ocb = 0; ocb < 2; ++ocb)
#pragma unroll
        for (int pcb = 0; pcb < 2; ++pcb)
#pragma unroll
            for (int reg = 0; reg < 16; ++reg) {
                const int row = (reg & 3) + 8 * (reg >> 2) + rgh;
                const int oc = wm * 64 + ocb * 32 + row;
                float v = acc1[ocb][pcb][reg] + acc2[ocb][pcb][reg] * 4.8828125e-4f + bsh[oc];
                hn[(size_t)oc * 4096 + pcb * 32 + colw] = fmaxf(v, 0.0f);
            }
}

// ---------------- 1x1 heads — unchanged (verified) ----------------
__global__ __launch_bounds__(256) void k_heads(const float* __restrict__ h,
                                               const float* __restrict__ loc_w,
                                               const float* __restrict__ score_w,
                                               const float* __restrict__ loc_b,
                                               const float* __restrict__ score_b,
                                               const int* __restrict__ ihp,
                                               const int* __restrict__ iwp,
                                               float* __restrict__ out,
                                               float* __restrict__ boxes,
                                               unsigned int* __restrict__ ubuf) {
    __shared__ float Wl[54 * 64];     // [c][kk]
    __shared__ float outb[128 * 57];  // [p][c] pitch 57
    const int tid = threadIdx.x;
    const int pl = tid & 127, chalf = tid >> 7;
    const int c0 = chalf * 27;
    const int ptile = blockIdx.x;
    const int n = blockIdx.y;
    const int pg = ptile * 128 + pl;

    float acc[27];
#pragma unroll
    for (int i = 0; i < 27; ++i) acc[i] = 0.f;

    for (int kc = 0; kc < 4; ++kc) {
        __syncthreads();
        for (int idx = tid; idx < 54 * 64; idx += 256) {
            int c = idx >> 6, kk = idx & 63;
            int gk = kc * 64 + kk;
            Wl[idx] = (c < 36) ? loc_w[c * 256 + gk] : score_w[(c - 36) * 256 + gk];
        }
        __syncthreads();
        for (int k4 = 0; k4 < 64; k4 += 4) {
            int gk = kc * 64 + k4;
            float hv0 = h[(n * 256 + gk + 0) * 4096 + pg];
            float hv1 = h[(n * 256 + gk + 1) * 4096 + pg];
            float hv2 = h[(n * 256 + gk + 2) * 4096 + pg];
            float hv3 = h[(n * 256 + gk + 3) * 4096 + pg];
#pragma unroll
            for (int ci = 0; ci < 27; ++ci) {
                float4 w4 = *(const float4*)&Wl[(c0 + ci) * 64 + k4];
                acc[ci] += hv0 * w4.x + hv1 * w4.y + hv2 * w4.z + hv3 * w4.w;
            }
        }
    }
#pragma unroll
    for (int ci = 0; ci < 27; ++ci) {
        int c = c0 + ci;
        float bv = (c < 36) ? loc_b[c] : score_b[c - 36];
        outb[pl * 57 + c] = acc[ci] + bv;
    }
    __syncthreads();

    const float fh = (float)(*ihp), fwid = (float)(*iwp);
    for (int slot = tid; slot < 128 * 9; slot += 256) {
        int pli = slot / 9, a = slot - pli * 9;
        int p = ptile * 128 + pli;
        int y = p >> 6, xg = p & 63;
        float l0 = outb[pli * 57 + a * 4 + 0];
        float l1 = outb[pli * 57 + a * 4 + 1];
        float l2 = outb[pli * 57 + a * 4 + 2];
        float l3 = outb[pli * 57 + a * 4 + 3];
        float s0 = outb[pli * 57 + 36 + a * 2 + 0];
        float s1 = outb[pli * 57 + 36 + a * 2 + 1];
        size_t base = (size_t)n * NANCH + (size_t)p * 9 + a;
        ((float4*)(out + OUT_LOC))[base] = make_float4(l0, l1, l2, l3);
        ((float2*)(out + OUT_SCORE))[base] = make_float2(s0, s1);
        float mx = fmaxf(s0, s1);
        float e0 = expf(s0 - mx), e1 = expf(s1 - mx);
        float fg = e1 / (e0 + e1);
        double rr = (a < 3) ? 0.5 : ((a < 6) ? 1.0 : 2.0);
        int sj = a % 3;
        double ssc = (sj == 0) ? 8.0 : ((sj == 1) ? 16.0 : 32.0);
        double hhd = 7.0 * ssc * sqrt(rr);
        double wwd = 7.0 * ssc * sqrt(1.0 / rr);
        float a0 = (float)(3.5 - 0.5 * hhd), a2 = (float)(3.5 + 0.5 * hhd);
        float b0 = (float)(3.5 - 0.5 * wwd), b2 = (float)(3.5 + 0.5 * wwd);
        float ay1 = y * 16.0f + a0, ay2 = y * 16.0f + a2;
        float ax1 = xg * 16.0f + b0, ax2 = xg * 16.0f + b2;
        float ah = ay2 - ay1, aw = ax2 - ax1;
        float acy = ay1 + 0.5f * ah, acx = ax1 + 0.5f * aw;
        float cy = l0 * ah + acy, cx = l1 * aw + acx;
        float bh = expf(l2) * ah, bw = expf(l3) * aw;
        float y1 = fminf(fmaxf(cy - 0.5f * bh, 0.f), fh);
        float x1 = fminf(fmaxf(cx - 0.5f * bw, 0.f), fwid);
        float y2 = fminf(fmaxf(cy + 0.5f * bh, 0.f), fh);
        float x2 = fminf(fmaxf(cx + 0.5f * bw, 0.f), fwid);
        ((float4*)boxes)[base] = make_float4(y1, x1, y2, x2);
        bool valid = ((y2 - y1) >= 16.0f) && ((x2 - x1) >= 16.0f);
        float sc = valid ? fg : -__builtin_inff();
        unsigned int ub = __float_as_uint(sc);
        ub = (ub & 0x80000000u) ? ~ub : (ub | 0x80000000u);
        ubuf[base] = ub;
    }
}

// ---------------- exact top-6000 per batch: byte-radix select + compact (unchanged) ----------------
__global__ __launch_bounds__(1024) void k_select(const unsigned int* __restrict__ ubuf,
                                                 unsigned long long* __restrict__ ckeys,
                                                 unsigned int* __restrict__ cc) {
    __shared__ unsigned int hist[256];
    __shared__ unsigned int selb;
    __shared__ int rank_s;
    __shared__ unsigned int lcnt;
    const int tid = threadIdx.x;
    const int b = blockIdx.x;
    const unsigned int* ub = ubuf + (size_t)b * NANCH;
    if (tid == 0) { rank_s = NPRE - 1; lcnt = 0; }
    unsigned int prefix = 0;
    for (int pass = 0; pass < 4; ++pass) {
        int shift = 24 - 8 * pass;
        if (tid < 256) hist[tid] = 0;
        __syncthreads();
        for (int i = tid; i < NANCH; i += 1024) {
            unsigned int u = ub[i];
            bool ok = (pass == 0) || ((u >> (shift + 8)) == (prefix >> (shift + 8)));
            if (ok) atomicAdd(&hist[(u >> shift) & 255], 1u);
        }
        __syncthreads();
        if (tid == 0) {
            int racc = 0; unsigned int bs = 0; int r = rank_s;
            for (int bb = 255; bb >= 0; --bb) {
                int c = (int)hist[bb];
                if (racc + c > r) { bs = (unsigned int)bb; rank_s = r - racc; break; }
                racc += c;
            }
            selb = bs;
        }
        __syncthreads();
        prefix |= (selb << shift);
        __syncthreads();
    }
    const unsigned int ustar = prefix;
    for (int i = tid; i < NANCH; i += 1024) {
        unsigned int u = ub[i];
        if (u >= ustar) {
            unsigned int pos = atomicAdd(&lcnt, 1u);
            if (pos < 8192)
                ckeys[(size_t)b * 8192 + pos] =
                    ((unsigned long long)u << 32) | (unsigned int)(0xFFFFFFFFu - (unsigned int)i);
        }
    }
    __syncthreads();
    if (tid == 0) cc[b] = (lcnt > 8192u) ? 8192u : lcnt;
}

// ---------------- bitonic sort 8192: in-register (8 keys/thread) + shuffle + minimal LDS ----------------
// Same network/compare semantics as the previous pure-LDS version -> bit-identical result.
// Stages j in {1,2,4}: in-register (static indices). j in {8..256}: __shfl_xor within wave.
// j in {512..4096}: LDS exchange (10 stages, 20 barriers total vs 182 before).
__device__ __forceinline__ void cswap_u64(unsigned long long& a, unsigned long long& c, bool desc) {
    bool sw = desc ? (a < c) : (a > c);
    unsigned long long t0 = sw ? c : a;
    unsigned long long t1 = sw ? a : c;
    a = t0; c = t1;
}
__device__ __forceinline__ void net8(unsigned long long v[8], bool d) {
    cswap_u64(v[0], v[4], d); cswap_u64(v[1], v[5], d); cswap_u64(v[2], v[6], d); cswap_u64(v[3], v[7], d);
    cswap_u64(v[0], v[2], d); cswap_u64(v[1], v[3], d); cswap_u64(v[4], v[6], d); cswap_u64(v[5], v[7], d);
    cswap_u64(v[0], v[1], d); cswap_u64(v[2], v[3], d); cswap_u64(v[4], v[5], d); cswap_u64(v[6], v[7], d);
}
__device__ __forceinline__ unsigned long long shfl_xor_u64(unsigned long long x, int lmask) {
    unsigned int lo = (unsigned int)x, hi = (unsigned int)(x >> 32);
    lo = __shfl_xor(lo, lmask, 64);
    hi = __shfl_xor(hi, lmask, 64);
    return ((unsigned long long)hi << 32) | lo;
}
__global__ __launch_bounds__(1024) void k_sort(const unsigned long long* __restrict__ ckeys,
                                               const unsigned int* __restrict__ cc,
                                               const float* __restrict__ boxes,
                                               float* __restrict__ bk) {
    __shared__ unsigned long long S[8192];
    const int tid = threadIdx.x;
    const int b = blockIdx.x;
    const int cnt = (int)cc[b];
    const int base = tid * 8;

    unsigned long long v[8];
#pragma unroll
    for (int e = 0; e < 8; ++e) {
        int i = base + e;
        v[e] = (i < cnt) ? ckeys[(size_t)b * 8192 + i] : 0ull;
    }

    // k=2  (desc pattern over e: T,F,T,F)
    cswap_u64(v[0], v[1], true);  cswap_u64(v[2], v[3], false);
    cswap_u64(v[4], v[5], true);  cswap_u64(v[6], v[7], false);
    // k=4  (desc: e<4 -> T, else F)
    cswap_u64(v[0], v[2], true);  cswap_u64(v[1], v[3], true);
    cswap_u64(v[4], v[6], false); cswap_u64(v[5], v[7], false);
    cswap_u64(v[0], v[1], true);  cswap_u64(v[2], v[3], true);
    cswap_u64(v[4], v[5], false); cswap_u64(v[6], v[7], false);
    // k=8  (desc uniform per thread: tid even -> T)
    net8(v, (tid & 1) == 0);

    for (int k = 16; k <= 8192; k <<= 1) {
        for (int j = k >> 1; j >= 8; j >>= 1) {
            const bool keep_max = (((base & k) == 0) != ((base & j) != 0));
            if (j >= 512) {
                __syncthreads();   // previous stage's reads complete before overwrite
#pragma unroll
                for (int e = 0; e < 8; ++e) S[base + e] = v[e];
                __syncthreads();
                const int pb = base ^ j;
#pragma unroll
                for (int e = 0; e < 8; ++e) {
                    unsigned long long p = S[pb + e];
                    v[e] = keep_max ? (v[e] >= p ? v[e] : p) : (v[e] <= p ? v[e] : p);
                }
            } else {
                const int lmask = j >> 3;
#pragma unroll
                for (int e = 0; e < 8; ++e) {
                    unsigned long long p = shfl_xor_u64(v[e], lmask);
                    v[e] = keep_max ? (v[e] >= p ? v[e] : p) : (v[e] <= p ? v[e] : p);
                }
            }
        }
        net8(v, (base & k) == 0);
    }

    // gather boxes for ranks < NPRE directly from registers
#pragma unroll
    for (int e = 0; e < 8; ++e) {
        int i = base + e;
        if (i < NPRE) {
            unsigned long long key = v[e];
            unsigned int idx = 0xFFFFFFFFu - (unsigned int)(key & 0xFFFFFFFFull);
            if (idx >= NANCH) idx = NANCH - 1;   // safety
            float4 bx = ((const float4*)boxes)[(size_t)b * NANCH + idx];
            ((float4*)bk)[(size_t)b * NPRE + i] = bx;
        }
    }
}

// ---------------- IoU bitmask, COLUMN-major (unchanged) ----------------
__global__ __launch_bounds__(256) void k_mask(const float* __restrict__ bk,
                                              unsigned long long* __restrict__ MT) {
    const int iw = blockIdx.x;
    const int gb = blockIdx.y;
    const int b = blockIdx.z;
    if (iw > 4 * gb + 3) return;
    const int tid = threadIdx.x;
    __shared__ float4 jb[64];
    if (tid < 64) {
        int j = iw * 64 + tid;
        jb[tid] = (j < NPRE) ? ((const float4*)bk)[(size_t)b * NPRE + j]
                             : make_float4(0.f, 0.f, 0.f, 0.f);
    }
    __syncthreads();
    const int g = gb * 256 + tid;
    float4 bi = (g < NPRE) ? ((const float4*)bk)[(size_t)b * NPRE + g]
                           : make_float4(0.f, 0.f, 0.f, 0.f);
    float ai = (bi.z - bi.x) * (bi.w - bi.y);
    unsigned long long word = 0ull;
#pragma unroll 4
    for (int jj = 0; jj < 64; ++jj) {
        float4 bj = jb[jj];
        float ty = fmaxf(bi.x, bj.x), tx = fmaxf(bi.y, bj.y);
        float by = fminf(bi.z, bj.z), bx = fminf(bi.w, bj.w);
        float ihh = fmaxf(by - ty, 0.f), iww = fmaxf(bx - tx, 0.f);
        float inter = ihh * iww;
        float aj = (bj.z - bj.x) * (bj.w - bj.y);
        float iou = inter / (ai + aj - inter + 1e-9f);
        if (iou > 0.7f) word |= (1ull << jj);
    }
    if (g < GCOLS)
        MT[((size_t)b * NWORDS + iw) * GCOLS + g] = word;
}

// ---------------- greedy NMS with early break (unchanged) ----------------
__global__ __launch_bounds__(1024) void k_nms(const unsigned long long* __restrict__ MT,
                                              const float* __restrict__ bk,
                                              float* __restrict__ out) {
    const int b = blockIdx.x;
    const int tid = threadIdx.x;
    const int lane = tid & 63;
    __shared__ unsigned long long keptw[NWORDS];
    __shared__ unsigned long long dead[NWORDS];
    __shared__ int sel[NPOST];
    __shared__ int totkept;
    const unsigned long long* mtb = MT + (size_t)b * NWORDS * GCOLS;

    for (int i = tid; i < NWORDS; i += 1024) { dead[i] = 0ull; keptw[i] = 0ull; }
    if (tid == 0) totkept = 0;
    __syncthreads();

    for (int c = 0; c < NWORDS; ++c) {
        if (tid < 64) {   // wave 0: in-chunk greedy closure
            const int g = c * 64 + lane;
            unsigned long long diag = mtb[(size_t)c * GCOLS + g];
            bool deadl = (((dead[c] >> lane) & 1ull) != 0ull) || (g >= NPRE);
            unsigned long long undec = ~__ballot(deadl);
            unsigned long long kc = 0ull;
            while (undec) {
                int i = __builtin_ctzll(undec);
                kc |= (1ull << i);
                unsigned long long supm = __ballot((diag >> i) & 1ull);
                undec &= ~(supm | (1ull << i));
            }
            if (lane == 0) { keptw[c] = kc; totkept += __popcll(kc); }
        }
        __syncthreads();
        if (totkept >= NPOST) break;          // later chunks can't affect the output
        const unsigned long long kc = keptw[c];
        if (kc) {
            for (int g2 = (c + 1) * 64 + tid; g2 < GCOLS; g2 += 1024) {
                unsigned long long w = mtb[(size_t)c * GCOLS + g2] & kc;
                unsigned long long m = __ballot(w != 0ull);
                if (lane == 0 && m) atomicOr(&dead[g2 >> 6], m);
            }
        }
        __syncthreads();
    }

    if (tid == 0) {
        int pos = 0;
        for (int w = 0; w < NWORDS && pos < NPOST; ++w) {
            unsigned long long kw = keptw[w];
            while (kw && pos < NPOST) {
                int i2 = __builtin_ctzll(kw);
                sel[pos++] = w * 64 + i2;
                kw &= kw - 1;
            }
        }
        for (int w = 0; w < NWORDS && pos < NPOST; ++w) {
            int nvalid = NPRE - w * 64; if (nvalid > 64) nvalid = 64;
            unsigned long long vm = (nvalid >= 64) ? ~0ull : ((1ull << nvalid) - 1ull);
            unsigned long long sw = (~keptw[w]) & vm;
            while (sw && pos < NPOST) {
                int i2 = __builtin_ctzll(sw);
                sel[pos++] = w * 64 + i2;
                sw &= sw - 1;
            }
        }
    }
    __syncthreads();
    for (int s2 = tid; s2 < NPOST; s2 += 1024) {
        int i = sel[s2];
        float4 bx = ((const float4*)bk)[(size_t)b * NPRE + i];
        ((float4*)(out + OUT_ROIS))[b * NPOST + s2] = bx;
        out[OUT_RIDX + b * NPOST + s2] = (float)b;
    }
}

// ---------------- launch ----------------
extern "C" void kernel_launch(void* const* d_in, const int* in_sizes, int n_in,
                              void* d_out, int out_size, void* d_ws, size_t ws_size,
                              hipStream_t stream) {
    const float* x = (const float*)d_in[0];
    const float* conv1_w = (const float*)d_in[1];
    const float* conv1_b = (const float*)d_in[2];
    const float* score_w = (const float*)d_in[3];
    const float* score_b = (const float*)d_in[4];
    const float* loc_w = (const float*)d_in[5];
    const float* loc_b = (const float*)d_in[6];
    const int* ihp = (const int*)d_in[7];
    const int* iwp = (const int*)d_in[8];
    float* out = (float*)d_out;
    char* ws = (char*)d_ws;
    float* h = (float*)(ws + H_OFF);
    _Float16* w3h = (_Float16*)(ws + WT_OFF);
    _Float16* w3l = (_Float16*)(ws + WT_OFF + 1179648ul);
    float* boxes = (float*)(ws + BOX_OFF);
    unsigned int* ubuf = (unsigned int*)(ws + U_OFF);
    unsigned long long* ckeys = (unsigned long long*)(ws + CK_OFF);
    unsigned int* cc = (unsigned int*)(ws + CC_OFF);
    float* bk = (float*)(ws + BK_OFF);
    unsigned long long* MT = (unsigned long long*)(ws + M_OFF);

    hipLaunchKernelGGL(k_prep_w, dim3(2304), dim3(256), 0, stream, conv1_w, w3h, w3l);
    hipLaunchKernelGGL(k_anchors, dim3(144), dim3(256), 0, stream, out, cc);
    hipLaunchKernelGGL(k_conv1m, dim3(32, 8), dim3(512), 0, stream, x, w3h, w3l, conv1_b, h);
    hipLaunchKernelGGL(k_heads, dim3(32, 8), dim3(256), 0, stream,
                       h, loc_w, score_w, loc_b, score_b, ihp, iwp, out, boxes, ubuf);
    hipLaunchKernelGGL(k_select, dim3(8), dim3(1024), 0, stream, ubuf, ckeys, cc);
    hipLaunchKernelGGL(k_sort, dim3(8), dim3(1024), 0, stream, ckeys, cc, boxes, bk);
    hipLaunchKernelGGL(k_mask, dim3(94, 24, 8), dim3(256), 0, stream, bk, MT);
    hipLaunchKernelGGL(k_nms, dim3(8), dim3(1024), 0, stream, MT, bk, out);
}

// Round 4
// 587.588 us; speedup vs baseline: 1.8495x; 1.0612x over previous
//
#include <hip/hip_runtime.h>
#include <cstdint>
#include <cstddef>

// ---------------- problem constants ----------------
#define NBATCH 8
#define MID 256
#define HIMG 64
#define WIMG 64
#define NA 9
#define NPRE 6000
#define NPOST 300
#define NANCH (HIMG*WIMG*NA)   // 36864
#define NWORDS 94              // ceil(6000/64)
#define GCOLS 6016             // 94*64 padded columns

// output float offsets
#define OUT_LOC   0
#define OUT_SCORE 1179648
#define OUT_ROIS  1769472
#define OUT_RIDX  1779072
#define OUT_ANCH  1781472

// workspace byte offsets
#define H_OFF    0ul
#define H_BYTES  (8ul*256*64*64*4)         // 33554432
#define WT_OFF   (H_OFF + H_BYTES)
#define WT_BYTES (2304ul*256*4)            // 2359296 = exactly w3h+w3l (half)
#define BOX_OFF  (WT_OFF + WT_BYTES)
#define BOX_BYTES (8ul*36864*4*4)          // 4718592
#define U_OFF    (BOX_OFF + BOX_BYTES)
#define U_BYTES  (8ul*36864*4)
#define CK_OFF   (U_OFF + U_BYTES)
#define CK_BYTES (8ul*8192*8)
#define CC_OFF   (CK_OFF + CK_BYTES)
#define CC_BYTES 64ul
#define BK_OFF   (CC_OFF + CC_BYTES)
#define BK_BYTES (8ul*6000*16)
#define M_OFF    (BK_OFF + BK_BYTES + 64)
#define M_BYTES  (8ul*NWORDS*GCOLS*8)      // 36.2 MB, column-major mask

typedef _Float16 f16x8 __attribute__((ext_vector_type(8)));
typedef float f32x16 __attribute__((ext_vector_type(16)));

// ---------------- weight prep: conv1_w[oc][ic][ky][kx] -> w3{h,l}[s][kb][g][oc][8] fp16 hi/lo ----------
__global__ __launch_bounds__(256) void k_prep_w(const float* __restrict__ w,
                                                _Float16* __restrict__ w3h,
                                                _Float16* __restrict__ w3l) {
    int idx = blockIdx.x * 256 + threadIdx.x;   // 589824 = 9*16*2*256*8
    if (idx >= 589824) return;
    int e  = idx & 7;
    int t  = idx >> 3;
    int oc = t & 255; t >>= 8;
    int g  = t & 1;   t >>= 1;
    int kb = t & 15;  t >>= 4;
    int s  = t;                               // 0..8
    int ic = kb * 16 + g * 8 + e;
    float v = w[(oc * 256 + ic) * 9 + s];
    _Float16 vh = (_Float16)v;
    float r = v - (float)vh;                  // exact in fp32
    w3h[idx] = vh;
    w3l[idx] = (_Float16)(r * 2048.0f);
}

// ---------------- anchors output (exact double->f32 like numpy) + zero counters ----------------
__global__ void k_anchors(float* __restrict__ out, unsigned int* __restrict__ cc) {
    int idx = blockIdx.x * 256 + threadIdx.x;
    if (blockIdx.x == 0 && threadIdx.x < 16) cc[threadIdx.x] = 0u;
    if (idx >= NANCH) return;
    int p = idx / 9, a = idx - p * 9;
    int y = p >> 6, xg = p & 63;
    double rr = (a < 3) ? 0.5 : ((a < 6) ? 1.0 : 2.0);
    int sj = a % 3;
    double ssc = (sj == 0) ? 8.0 : ((sj == 1) ? 16.0 : 32.0);
    double hh = 7.0 * ssc * sqrt(rr);
    double ww = 7.0 * ssc * sqrt(1.0 / rr);
    float a0 = (float)(3.5 - 0.5 * hh), a2 = (float)(3.5 + 0.5 * hh);
    float b0 = (float)(3.5 - 0.5 * ww), b2 = (float)(3.5 + 0.5 * ww);
    float* dst = out + OUT_ANCH + (size_t)idx * 4;
    dst[0] = y * 16.0f + a0;
    dst[1] = xg * 16.0f + b0;
    dst[2] = y * 16.0f + a2;
    dst[3] = xg * 16.0f + b2;
}

// ---------------- conv1 3x3 + bias + relu via fp16 hi/lo split MFMA (unchanged) ----------------
__global__ __launch_bounds__(512, 2) void k_conv1m(const float* __restrict__ x,
                                                   const _Float16* __restrict__ w3h,
                                                   const _Float16* __restrict__ w3l,
                                                   const float* __restrict__ bias,
                                                   float* __restrict__ h) {
    __shared__ __align__(16) _Float16 bt0[4 * 66 * 26];   // hi
    __shared__ __align__(16) _Float16 bt1[4 * 66 * 26];   // lo
    __shared__ float bsh[256];

    const int tid = threadIdx.x;
    const int lane = tid & 63;
    const int wv = tid >> 6;        // 0..7
    const int wm = wv >> 1;         // 0..3 : oc block 64*wm
    const int wn = wv & 1;          // 0..1 : image row y0+wn
    const int y0 = blockIdx.x * 2;
    const int n  = blockIdx.y;
    const int bl31 = lane & 31;
    const int g = lane >> 5;        // ic-subgroup for fragments

    for (int i = tid; i < 858; i += 512) {
        ((f16x8*)bt0)[i] = (f16x8){};
        ((f16x8*)bt1)[i] = (f16x8){};
    }
    if (tid < 256) bsh[tid] = bias[tid];

    f32x16 acc1[2][2], acc2[2][2];
#pragma unroll
    for (int i = 0; i < 2; ++i)
#pragma unroll
        for (int j = 0; j < 2; ++j)
#pragma unroll
            for (int e = 0; e < 16; ++e) { acc1[i][j][e] = 0.0f; acc2[i][j][e] = 0.0f; }

    const int scol = lane;
    const int sr   = wv & 3;
    const int siig = wv >> 2;
    const int sgy  = y0 - 1 + sr;
    const bool gyok = (sgy >= 0) && (sgy < 64);
    const float* xrow = x + (size_t)n * 1048576 + sgy * 64 + scol;
    const int bto = (sr * 66 + scol + 1) * 26 + siig * 8;

    const int aoffl = (g * 256 + wm * 64 + bl31) * 8;

    float xr[8];
#pragma unroll
    for (int q = 0; q < 8; ++q)
        xr[q] = gyok ? xrow[(size_t)(siig * 8 + q) * 4096] : 0.0f;

    for (int kb = 0; kb < 16; ++kb) {
        __syncthreads();
        {
            f16x8 hh, hl;
#pragma unroll
            for (int q = 0; q < 8; ++q) {
                float v = xr[q];
                _Float16 vh = (_Float16)v;
                hh[q] = vh;
                hl[q] = (_Float16)((v - (float)vh) * 2048.0f);
            }
            *(f16x8*)&bt0[bto] = hh;
            *(f16x8*)&bt1[bto] = hl;
        }
        __syncthreads();
        if (kb < 15) {
#pragma unroll
            for (int q = 0; q < 8; ++q)
                xr[q] = gyok ? xrow[(size_t)((kb + 1) * 16 + siig * 8 + q) * 4096] : 0.0f;
        }
        const _Float16* wkh = w3h + (size_t)kb * 4096;
        const _Float16* wkl = w3l + (size_t)kb * 4096;
#pragma unroll
        for (int s = 0; s < 9; ++s) {
            const _Float16* ph = wkh + (size_t)s * 65536;
            const _Float16* pl = wkl + (size_t)s * 65536;
            f16x8 Ah0 = *(const f16x8*)(ph + aoffl);
            f16x8 Ah1 = *(const f16x8*)(ph + aoffl + 256);
            f16x8 Al0 = *(const f16x8*)(pl + aoffl);
            f16x8 Al1 = *(const f16x8*)(pl + aoffl + 256);

            const int dy = s / 3 - 1, dx = s % 3 - 1;
            const int entry0 = (wn + dy + 1) * 66 + dx + 1 + bl31;
            const int e0 = entry0 * 26 + g * 8;
            const int e1 = (entry0 + 32) * 26 + g * 8;
            f16x8 Bh0 = *(const f16x8*)&bt0[e0];
            f16x8 Bl0 = *(const f16x8*)&bt1[e0];
            f16x8 Bh1 = *(const f16x8*)&bt0[e1];
            f16x8 Bl1 = *(const f16x8*)&bt1[e1];

            acc1[0][0] = __builtin_amdgcn_mfma_f32_32x32x16_f16(Ah0, Bh0, acc1[0][0], 0, 0, 0);
            acc1[0][1] = __builtin_amdgcn_mfma_f32_32x32x16_f16(Ah0, Bh1, acc1[0][1], 0, 0, 0);
            acc1[1][0] = __builtin_amdgcn_mfma_f32_32x32x16_f16(Ah1, Bh0, acc1[1][0], 0, 0, 0);
            acc1[1][1] = __builtin_amdgcn_mfma_f32_32x32x16_f16(Ah1, Bh1, acc1[1][1], 0, 0, 0);
            acc2[0][0] = __builtin_amdgcn_mfma_f32_32x32x16_f16(Ah0, Bl0, acc2[0][0], 0, 0, 0);
            acc2[0][1] = __builtin_amdgcn_mfma_f32_32x32x16_f16(Ah0, Bl1, acc2[0][1], 0, 0, 0);
            acc2[1][0] = __builtin_amdgcn_mfma_f32_32x32x16_f16(Ah1, Bl0, acc2[1][0], 0, 0, 0);
            acc2[1][1] = __builtin_amdgcn_mfma_f32_32x32x16_f16(Ah1, Bl1, acc2[1][1], 0, 0, 0);
            acc2[0][0] = __builtin_amdgcn_mfma_f32_32x32x16_f16(Al0, Bh0, acc2[0][0], 0, 0, 0);
            acc2[0][1] = __builtin_amdgcn_mfma_f32_32x32x16_f16(Al0, Bh1, acc2[0][1], 0, 0, 0);
            acc2[1][0] = __builtin_amdgcn_mfma_f32_32x32x16_f16(Al1, Bh0, acc2[1][0], 0, 0, 0);
            acc2[1][1] = __builtin_amdgcn_mfma_f32_32x32x16_f16(Al1, Bh1, acc2[1][1], 0, 0, 0);
        }
    }

    const int colw = lane & 31;
    const int rgh = (lane >> 5) * 4;
    float* hn = h + (size_t)n * 1048576 + (size_t)(y0 + wn) * 64;
#pragma unroll
    for (int ocb = 0; ocb < 2; ++ocb)
#pragma unroll
        for (int pcb = 0; pcb < 2; ++pcb)
#pragma unroll
            for (int reg = 0; reg < 16; ++reg) {
                const int row = (reg & 3) + 8 * (reg >> 2) + rgh;
                const int oc = wm * 64 + ocb * 32 + row;
                float v = acc1[ocb][pcb][reg] + acc2[ocb][pcb][reg] * 4.8828125e-4f + bsh[oc];
                hn[(size_t)oc * 4096 + pcb * 32 + colw] = fmaxf(v, 0.0f);
            }
}

// ---------------- 1x1 heads — unchanged (verified) ----------------
__global__ __launch_bounds__(256) void k_heads(const float* __restrict__ h,
                                               const float* __restrict__ loc_w,
                                               const float* __restrict__ score_w,
                                               const float* __restrict__ loc_b,
                                               const float* __restrict__ score_b,
                                               const int* __restrict__ ihp,
                                               const int* __restrict__ iwp,
                                               float* __restrict__ out,
                                               float* __restrict__ boxes,
                                               unsigned int* __restrict__ ubuf) {
    __shared__ float Wl[54 * 64];     // [c][kk]
    __shared__ float outb[128 * 57];  // [p][c] pitch 57
    const int tid = threadIdx.x;
    const int pl = tid & 127, chalf = tid >> 7;
    const int c0 = chalf * 27;
    const int ptile = blockIdx.x;
    const int n = blockIdx.y;
    const int pg = ptile * 128 + pl;

    float acc[27];
#pragma unroll
    for (int i = 0; i < 27; ++i) acc[i] = 0.f;

    for (int kc = 0; kc < 4; ++kc) {
        __syncthreads();
        for (int idx = tid; idx < 54 * 64; idx += 256) {
            int c = idx >> 6, kk = idx & 63;
            int gk = kc * 64 + kk;
            Wl[idx] = (c < 36) ? loc_w[c * 256 + gk] : score_w[(c - 36) * 256 + gk];
        }
        __syncthreads();
        for (int k4 = 0; k4 < 64; k4 += 4) {
            int gk = kc * 64 + k4;
            float hv0 = h[(n * 256 + gk + 0) * 4096 + pg];
            float hv1 = h[(n * 256 + gk + 1) * 4096 + pg];
            float hv2 = h[(n * 256 + gk + 2) * 4096 + pg];
            float hv3 = h[(n * 256 + gk + 3) * 4096 + pg];
#pragma unroll
            for (int ci = 0; ci < 27; ++ci) {
                float4 w4 = *(const float4*)&Wl[(c0 + ci) * 64 + k4];
                acc[ci] += hv0 * w4.x + hv1 * w4.y + hv2 * w4.z + hv3 * w4.w;
            }
        }
    }
#pragma unroll
    for (int ci = 0; ci < 27; ++ci) {
        int c = c0 + ci;
        float bv = (c < 36) ? loc_b[c] : score_b[c - 36];
        outb[pl * 57 + c] = acc[ci] + bv;
    }
    __syncthreads();

    const float fh = (float)(*ihp), fwid = (float)(*iwp);
    for (int slot = tid; slot < 128 * 9; slot += 256) {
        int pli = slot / 9, a = slot - pli * 9;
        int p = ptile * 128 + pli;
        int y = p >> 6, xg = p & 63;
        float l0 = outb[pli * 57 + a * 4 + 0];
        float l1 = outb[pli * 57 + a * 4 + 1];
        float l2 = outb[pli * 57 + a * 4 + 2];
        float l3 = outb[pli * 57 + a * 4 + 3];
        float s0 = outb[pli * 57 + 36 + a * 2 + 0];
        float s1 = outb[pli * 57 + 36 + a * 2 + 1];
        size_t base = (size_t)n * NANCH + (size_t)p * 9 + a;
        ((float4*)(out + OUT_LOC))[base] = make_float4(l0, l1, l2, l3);
        ((float2*)(out + OUT_SCORE))[base] = make_float2(s0, s1);
        float mx = fmaxf(s0, s1);
        float e0 = expf(s0 - mx), e1 = expf(s1 - mx);
        float fg = e1 / (e0 + e1);
        double rr = (a < 3) ? 0.5 : ((a < 6) ? 1.0 : 2.0);
        int sj = a % 3;
        double ssc = (sj == 0) ? 8.0 : ((sj == 1) ? 16.0 : 32.0);
        double hhd = 7.0 * ssc * sqrt(rr);
        double wwd = 7.0 * ssc * sqrt(1.0 / rr);
        float a0 = (float)(3.5 - 0.5 * hhd), a2 = (float)(3.5 + 0.5 * hhd);
        float b0 = (float)(3.5 - 0.5 * wwd), b2 = (float)(3.5 + 0.5 * wwd);
        float ay1 = y * 16.0f + a0, ay2 = y * 16.0f + a2;
        float ax1 = xg * 16.0f + b0, ax2 = xg * 16.0f + b2;
        float ah = ay2 - ay1, aw = ax2 - ax1;
        float acy = ay1 + 0.5f * ah, acx = ax1 + 0.5f * aw;
        float cy = l0 * ah + acy, cx = l1 * aw + acx;
        float bh = expf(l2) * ah, bw = expf(l3) * aw;
        float y1 = fminf(fmaxf(cy - 0.5f * bh, 0.f), fh);
        float x1 = fminf(fmaxf(cx - 0.5f * bw, 0.f), fwid);
        float y2 = fminf(fmaxf(cy + 0.5f * bh, 0.f), fh);
        float x2 = fminf(fmaxf(cx + 0.5f * bw, 0.f), fwid);
        ((float4*)boxes)[base] = make_float4(y1, x1, y2, x2);
        bool valid = ((y2 - y1) >= 16.0f) && ((x2 - x1) >= 16.0f);
        float sc = valid ? fg : -__builtin_inff();
        unsigned int ub = __float_as_uint(sc);
        ub = (ub & 0x80000000u) ? ~ub : (ub | 0x80000000u);
        ubuf[base] = ub;
    }
}

// ---------------- exact top-6000 per batch: byte-radix select + compact (unchanged) ----------------
__global__ __launch_bounds__(1024) void k_select(const unsigned int* __restrict__ ubuf,
                                                 unsigned long long* __restrict__ ckeys,
                                                 unsigned int* __restrict__ cc) {
    __shared__ unsigned int hist[256];
    __shared__ unsigned int selb;
    __shared__ int rank_s;
    __shared__ unsigned int lcnt;
    const int tid = threadIdx.x;
    const int b = blockIdx.x;
    const unsigned int* ub = ubuf + (size_t)b * NANCH;
    if (tid == 0) { rank_s = NPRE - 1; lcnt = 0; }
    unsigned int prefix = 0;
    for (int pass = 0; pass < 4; ++pass) {
        int shift = 24 - 8 * pass;
        if (tid < 256) hist[tid] = 0;
        __syncthreads();
        for (int i = tid; i < NANCH; i += 1024) {
            unsigned int u = ub[i];
            bool ok = (pass == 0) || ((u >> (shift + 8)) == (prefix >> (shift + 8)));
            if (ok) atomicAdd(&hist[(u >> shift) & 255], 1u);
        }
        __syncthreads();
        if (tid == 0) {
            int racc = 0; unsigned int bs = 0; int r = rank_s;
            for (int bb = 255; bb >= 0; --bb) {
                int c = (int)hist[bb];
                if (racc + c > r) { bs = (unsigned int)bb; rank_s = r - racc; break; }
                racc += c;
            }
            selb = bs;
        }
        __syncthreads();
        prefix |= (selb << shift);
        __syncthreads();
    }
    const unsigned int ustar = prefix;
    for (int i = tid; i < NANCH; i += 1024) {
        unsigned int u = ub[i];
        if (u >= ustar) {
            unsigned int pos = atomicAdd(&lcnt, 1u);
            if (pos < 8192)
                ckeys[(size_t)b * 8192 + pos] =
                    ((unsigned long long)u << 32) | (unsigned int)(0xFFFFFFFFu - (unsigned int)i);
        }
    }
    __syncthreads();
    if (tid == 0) cc[b] = (lcnt > 8192u) ? 8192u : lcnt;
}

// ---------------- bitonic sort 8192: in-register (8 keys/thread) + shuffle + minimal LDS ----------------
__device__ __forceinline__ void cswap_u64(unsigned long long& a, unsigned long long& c, bool desc) {
    bool sw = desc ? (a < c) : (a > c);
    unsigned long long t0 = sw ? c : a;
    unsigned long long t1 = sw ? a : c;
    a = t0; c = t1;
}
__device__ __forceinline__ void net8(unsigned long long v[8], bool d) {
    cswap_u64(v[0], v[4], d); cswap_u64(v[1], v[5], d); cswap_u64(v[2], v[6], d); cswap_u64(v[3], v[7], d);
    cswap_u64(v[0], v[2], d); cswap_u64(v[1], v[3], d); cswap_u64(v[4], v[6], d); cswap_u64(v[5], v[7], d);
    cswap_u64(v[0], v[1], d); cswap_u64(v[2], v[3], d); cswap_u64(v[4], v[5], d); cswap_u64(v[6], v[7], d);
}
__device__ __forceinline__ unsigned long long shfl_xor_u64(unsigned long long x, int lmask) {
    unsigned int lo = (unsigned int)x, hi = (unsigned int)(x >> 32);
    lo = __shfl_xor(lo, lmask, 64);
    hi = __shfl_xor(hi, lmask, 64);
    return ((unsigned long long)hi << 32) | lo;
}
__global__ __launch_bounds__(1024) void k_sort(const unsigned long long* __restrict__ ckeys,
                                               const unsigned int* __restrict__ cc,
                                               const float* __restrict__ boxes,
                                               float* __restrict__ bk) {
    __shared__ unsigned long long S[8192];
    const int tid = threadIdx.x;
    const int b = blockIdx.x;
    const int cnt = (int)cc[b];
    const int base = tid * 8;

    unsigned long long v[8];
#pragma unroll
    for (int e = 0; e < 8; ++e) {
        int i = base + e;
        v[e] = (i < cnt) ? ckeys[(size_t)b * 8192 + i] : 0ull;
    }

    cswap_u64(v[0], v[1], true);  cswap_u64(v[2], v[3], false);
    cswap_u64(v[4], v[5], true);  cswap_u64(v[6], v[7], false);
    cswap_u64(v[0], v[2], true);  cswap_u64(v[1], v[3], true);
    cswap_u64(v[4], v[6], false); cswap_u64(v[5], v[7], false);
    cswap_u64(v[0], v[1], true);  cswap_u64(v[2], v[3], true);
    cswap_u64(v[4], v[5], false); cswap_u64(v[6], v[7], false);
    net8(v, (tid & 1) == 0);

    for (int k = 16; k <= 8192; k <<= 1) {
        for (int j = k >> 1; j >= 8; j >>= 1) {
            const bool keep_max = (((base & k) == 0) != ((base & j) != 0));
            if (j >= 512) {
                __syncthreads();
#pragma unroll
                for (int e = 0; e < 8; ++e) S[base + e] = v[e];
                __syncthreads();
                const int pb = base ^ j;
#pragma unroll
                for (int e = 0; e < 8; ++e) {
                    unsigned long long p = S[pb + e];
                    v[e] = keep_max ? (v[e] >= p ? v[e] : p) : (v[e] <= p ? v[e] : p);
                }
            } else {
                const int lmask = j >> 3;
#pragma unroll
                for (int e = 0; e < 8; ++e) {
                    unsigned long long p = shfl_xor_u64(v[e], lmask);
                    v[e] = keep_max ? (v[e] >= p ? v[e] : p) : (v[e] <= p ? v[e] : p);
                }
            }
        }
        net8(v, (base & k) == 0);
    }

#pragma unroll
    for (int e = 0; e < 8; ++e) {
        int i = base + e;
        if (i < NPRE) {
            unsigned long long key = v[e];
            unsigned int idx = 0xFFFFFFFFu - (unsigned int)(key & 0xFFFFFFFFull);
            if (idx >= NANCH) idx = NANCH - 1;   // safety
            float4 bx = ((const float4*)boxes)[(size_t)b * NANCH + idx];
            ((float4*)bk)[(size_t)b * NPRE + i] = bx;
        }
    }
}

// ---------------- IoU bitmask, COLUMN-major — division-free, bit-exact predicate ----------------
// RN32(inter/den) > 0.7f  <=>  inter/den >= m  (m = 0.7f + 2^-25, tie rounds up to even 0x3F333334)
// m has 25-bit mantissa, den 24-bit -> m*den exact in f64 -> comparison is bit-exact vs IEEE div.
__global__ __launch_bounds__(256) void k_mask(const float* __restrict__ bk,
                                              unsigned long long* __restrict__ MT) {
    const int iw = blockIdx.x;
    const int gb = blockIdx.y;
    const int b = blockIdx.z;
    if (iw > 4 * gb + 3) return;
    const int tid = threadIdx.x;
    __shared__ float4 jb[64];
    __shared__ float ja[64];
    if (tid < 64) {
        int j = iw * 64 + tid;
        float4 v = (j < NPRE) ? ((const float4*)bk)[(size_t)b * NPRE + j]
                              : make_float4(0.f, 0.f, 0.f, 0.f);
        jb[tid] = v;
        ja[tid] = (v.z - v.x) * (v.w - v.y);
    }
    __syncthreads();
    const int g = gb * 256 + tid;
    float4 bi = (g < NPRE) ? ((const float4*)bk)[(size_t)b * NPRE + g]
                           : make_float4(0.f, 0.f, 0.f, 0.f);
    float ai = (bi.z - bi.x) * (bi.w - bi.y);
    const double MD = (double)0.7f + 0x1p-25;   // exact rounding midpoint
    unsigned long long word = 0ull;
#pragma unroll 8
    for (int jj = 0; jj < 64; ++jj) {
        float4 bj = jb[jj];
        float aj = ja[jj];
        float ty = fmaxf(bi.x, bj.x), tx = fmaxf(bi.y, bj.y);
        float by = fminf(bi.z, bj.z), bx = fminf(bi.w, bj.w);
        float ihh = fmaxf(by - ty, 0.f), iww = fmaxf(bx - tx, 0.f);
        float inter = ihh * iww;
        float den = ai + aj - inter + 1e-9f;
        if ((double)inter >= MD * (double)den) word |= (1ull << jj);
    }
    if (g < GCOLS)
        MT[((size_t)b * NWORDS + iw) * GCOLS + g] = word;
}

// ---------------- greedy NMS with early break (unchanged) ----------------
__global__ __launch_bounds__(1024) void k_nms(const unsigned long long* __restrict__ MT,
                                              const float* __restrict__ bk,
                                              float* __restrict__ out) {
    const int b = blockIdx.x;
    const int tid = threadIdx.x;
    const int lane = tid & 63;
    __shared__ unsigned long long keptw[NWORDS];
    __shared__ unsigned long long dead[NWORDS];
    __shared__ int sel[NPOST];
    __shared__ int totkept;
    const unsigned long long* mtb = MT + (size_t)b * NWORDS * GCOLS;

    for (int i = tid; i < NWORDS; i += 1024) { dead[i] = 0ull; keptw[i] = 0ull; }
    if (tid == 0) totkept = 0;
    __syncthreads();

    for (int c = 0; c < NWORDS; ++c) {
        if (tid < 64) {   // wave 0: in-chunk greedy closure
            const int g = c * 64 + lane;
            unsigned long long diag = mtb[(size_t)c * GCOLS + g];
            bool deadl = (((dead[c] >> lane) & 1ull) != 0ull) || (g >= NPRE);
            unsigned long long undec = ~__ballot(deadl);
            unsigned long long kc = 0ull;
            while (undec) {
                int i = __builtin_ctzll(undec);
                kc |= (1ull << i);
                unsigned long long supm = __ballot((diag >> i) & 1ull);
                undec &= ~(supm | (1ull << i));
            }
            if (lane == 0) { keptw[c] = kc; totkept += __popcll(kc); }
        }
        __syncthreads();
        if (totkept >= NPOST) break;          // later chunks can't affect the output
        const unsigned long long kc = keptw[c];
        if (kc) {
            for (int g2 = (c + 1) * 64 + tid; g2 < GCOLS; g2 += 1024) {
                unsigned long long w = mtb[(size_t)c * GCOLS + g2] & kc;
                unsigned long long m = __ballot(w != 0ull);
                if (lane == 0 && m) atomicOr(&dead[g2 >> 6], m);
            }
        }
        __syncthreads();
    }

    if (tid == 0) {
        int pos = 0;
        for (int w = 0; w < NWORDS && pos < NPOST; ++w) {
            unsigned long long kw = keptw[w];
            while (kw && pos < NPOST) {
                int i2 = __builtin_ctzll(kw);
                sel[pos++] = w * 64 + i2;
                kw &= kw - 1;
            }
        }
        for (int w = 0; w < NWORDS && pos < NPOST; ++w) {
            int nvalid = NPRE - w * 64; if (nvalid > 64) nvalid = 64;
            unsigned long long vm = (nvalid >= 64) ? ~0ull : ((1ull << nvalid) - 1ull);
            unsigned long long sw = (~keptw[w]) & vm;
            while (sw && pos < NPOST) {
                int i2 = __builtin_ctzll(sw);
                sel[pos++] = w * 64 + i2;
                sw &= sw - 1;
            }
        }
    }
    __syncthreads();
    for (int s2 = tid; s2 < NPOST; s2 += 1024) {
        int i = sel[s2];
        float4 bx = ((const float4*)bk)[(size_t)b * NPRE + i];
        ((float4*)(out + OUT_ROIS))[b * NPOST + s2] = bx;
        out[OUT_RIDX + b * NPOST + s2] = (float)b;
    }
}

// ---------------- launch ----------------
extern "C" void kernel_launch(void* const* d_in, const int* in_sizes, int n_in,
                              void* d_out, int out_size, void* d_ws, size_t ws_size,
                              hipStream_t stream) {
    const float* x = (const float*)d_in[0];
    const float* conv1_w = (const float*)d_in[1];
    const float* conv1_b = (const float*)d_in[2];
    const float* score_w = (const float*)d_in[3];
    const float* score_b = (const float*)d_in[4];
    const float* loc_w = (const float*)d_in[5];
    const float* loc_b = (const float*)d_in[6];
    const int* ihp = (const int*)d_in[7];
    const int* iwp = (const int*)d_in[8];
    float* out = (float*)d_out;
    char* ws = (char*)d_ws;
    float* h = (float*)(ws + H_OFF);
    _Float16* w3h = (_Float16*)(ws + WT_OFF);
    _Float16* w3l = (_Float16*)(ws + WT_OFF + 1179648ul);
    float* boxes = (float*)(ws + BOX_OFF);
    unsigned int* ubuf = (unsigned int*)(ws + U_OFF);
    unsigned long long* ckeys = (unsigned long long*)(ws + CK_OFF);
    unsigned int* cc = (unsigned int*)(ws + CC_OFF);
    float* bk = (float*)(ws + BK_OFF);
    unsigned long long* MT = (unsigned long long*)(ws + M_OFF);

    hipLaunchKernelGGL(k_prep_w, dim3(2304), dim3(256), 0, stream, conv1_w, w3h, w3l);
    hipLaunchKernelGGL(k_anchors, dim3(144), dim3(256), 0, stream, out, cc);
    hipLaunchKernelGGL(k_conv1m, dim3(32, 8), dim3(512), 0, stream, x, w3h, w3l, conv1_b, h);
    hipLaunchKernelGGL(k_heads, dim3(32, 8), dim3(256), 0, stream,
                       h, loc_w, score_w, loc_b, score_b, ihp, iwp, out, boxes, ubuf);
    hipLaunchKernelGGL(k_select, dim3(8), dim3(1024), 0, stream, ubuf, ckeys, cc);
    hipLaunchKernelGGL(k_sort, dim3(8), dim3(1024), 0, stream, ckeys, cc, boxes, bk);
    hipLaunchKernelGGL(k_mask, dim3(94, 24, 8), dim3(256), 0, stream, bk, MT);
    hipLaunchKernelGGL(k_nms, dim3(8), dim3(1024), 0, stream, MT, bk, out);
}